// Round 1
// baseline (522.295 us; speedup 1.0000x reference)
//
#include <hip/hip_runtime.h>
#include <stdint.h>

#define S_LEN 2048
#define DM 2048
#define NH 16
#define DKH 128
#define NB 2
#define NROWS (NB * S_LEN)  // 4096

typedef unsigned short u16;
typedef __attribute__((ext_vector_type(8))) __bf16 bf16x8;
typedef __attribute__((ext_vector_type(4))) float f32x4;

__device__ __forceinline__ float bf2f(u16 u) {
  union { unsigned u; float f; } v; v.u = ((unsigned)u) << 16; return v.f;
}
__device__ __forceinline__ u16 f2bf(float f) {
  union { float f; unsigned u; } v; v.f = f;
  unsigned r = v.u + 0x7FFFu + ((v.u >> 16) & 1u);
  return (u16)(r >> 16);
}

// ---------------- elementwise cast fp32 -> bf16 (vectorized x4) ----------------
__global__ void cast_kernel(const float* __restrict__ in, u16* __restrict__ out, int n4) {
  int i = blockIdx.x * blockDim.x + threadIdx.x;
  if (i >= n4) return;
  float4 v = ((const float4*)in)[i];
  unsigned r0 = (unsigned)f2bf(v.x) | ((unsigned)f2bf(v.y) << 16);
  unsigned r1 = (unsigned)f2bf(v.z) | ((unsigned)f2bf(v.w) << 16);
  ((uint2*)out)[i] = make_uint2(r0, r1);
}

// ---------------- RoPE cos/sin table: [S][64] ----------------
__global__ void rope_table_kernel(float* __restrict__ cost, float* __restrict__ sint) {
  int idx = blockIdx.x * blockDim.x + threadIdx.x;
  if (idx >= S_LEN * 64) return;
  int s = idx >> 6, i = idx & 63;
  // inv_freq = exp(-log(10000) * 2i/128) = exp(-log(10000) * i/64)
  float inv = expf(-9.210340371976184f * (float)i * (1.0f / 64.0f));
  float fr = (float)s * inv;
  cost[idx] = cosf(fr);
  sint[idx] = sinf(fr);
}

// ---------------- RoPE apply, interleaved pairs, in-place on bf16 (4096x2048) ----------------
__global__ void rope_apply_kernel(u16* __restrict__ T, const float* __restrict__ cost,
                                  const float* __restrict__ sint) {
  int p = blockIdx.x * blockDim.x + threadIdx.x;
  if (p >= NROWS * 1024) return;
  int row = p >> 10, ci = p & 1023;   // ci = h*64 + i
  int i = ci & 63;
  int s = row & (S_LEN - 1);
  unsigned* addr = (unsigned*)(T + ((size_t)row * DM + ci * 2));
  unsigned v = *addr;
  float t1 = bf2f((u16)(v & 0xffff));
  float t2 = bf2f((u16)(v >> 16));
  float c = cost[s * 64 + i], sn = sint[s * 64 + i];
  float o1 = t1 * c - t2 * sn;
  float o2 = t1 * sn + t2 * c;
  *addr = (unsigned)f2bf(o1) | ((unsigned)f2bf(o2) << 16);
}

// ---------------- V transpose: (b,s,h,d) -> Vt[(b*16+h)*128 + d][s] ----------------
__global__ void transpose_v_kernel(const u16* __restrict__ V, u16* __restrict__ Vt) {
  __shared__ u16 tile[32][33];
  int bh = blockIdx.z;
  int b = bh >> 4, h = bh & 15;
  int s0 = blockIdx.y * 32, d0 = blockIdx.x * 32;
  int tx = threadIdx.x & 31, ty = threadIdx.x >> 5;  // 32 x 8
  for (int i = ty; i < 32; i += 8)
    tile[i][tx] = V[(size_t)(b * S_LEN + s0 + i) * DM + h * DKH + d0 + tx];
  __syncthreads();
  for (int i = ty; i < 32; i += 8)
    Vt[(size_t)(bh * DKH + d0 + i) * S_LEN + s0 + tx] = tile[tx][i];
}

// ---------------- GEMM C = A(MxK) * B(NxK)^T, bf16 in, OutT out ----------------
// 128x128 tile, BK=64, 4 waves (each 64x64 as 4x4 16x16 frags), reg-prefetch dbuf.
__device__ __forceinline__ void store_c(u16* C, size_t idx, float v) { C[idx] = f2bf(v); }
__device__ __forceinline__ void store_c(float* C, size_t idx, float v) { C[idx] = v; }

template <typename OutT>
__global__ __launch_bounds__(256) void gemm_bt_kernel(const u16* __restrict__ A,
                                                      const u16* __restrict__ B,
                                                      OutT* __restrict__ C,
                                                      int M, int N, int Kd) {
  __shared__ u16 Al[128][72];  // stride 144B (16B-aligned, 2-way bank alias = free)
  __shared__ u16 Bl[128][72];
  int tid = threadIdx.x;
  int lane = tid & 63, wave = tid >> 6;
  int lr = lane & 15, lg = lane >> 4;
  int wr = wave >> 1, wc = wave & 1;
  int tm = blockIdx.y * 128, tn = blockIdx.x * 128;

  int srow = tid >> 3;         // 0..31
  int scol = (tid & 7) * 8;    // 0..56

  const u16* Ag = A + (size_t)(tm + srow) * Kd + scol;
  const u16* Bg = B + (size_t)(tn + srow) * Kd + scol;

  f32x4 zero4 = {0.f, 0.f, 0.f, 0.f};
  f32x4 acc[4][4];
  for (int i = 0; i < 4; i++)
    for (int j = 0; j < 4; j++) acc[i][j] = zero4;

  bf16x8 ra[4], rb[4];
  int nk = Kd >> 6;

#pragma unroll
  for (int c = 0; c < 4; c++) {
    ra[c] = *(const bf16x8*)(Ag + (size_t)(c * 32) * Kd);
    rb[c] = *(const bf16x8*)(Bg + (size_t)(c * 32) * Kd);
  }
#pragma unroll
  for (int c = 0; c < 4; c++) {
    *(bf16x8*)&Al[c * 32 + srow][scol] = ra[c];
    *(bf16x8*)&Bl[c * 32 + srow][scol] = rb[c];
  }
  __syncthreads();

  for (int t = 0; t < nk; t++) {
    if (t + 1 < nk) {
      const u16* Ag2 = Ag + (size_t)(t + 1) * 64;
      const u16* Bg2 = Bg + (size_t)(t + 1) * 64;
#pragma unroll
      for (int c = 0; c < 4; c++) {
        ra[c] = *(const bf16x8*)(Ag2 + (size_t)(c * 32) * Kd);
        rb[c] = *(const bf16x8*)(Bg2 + (size_t)(c * 32) * Kd);
      }
    }
#pragma unroll
    for (int kk = 0; kk < 2; kk++) {
      bf16x8 af[4], bfr[4];
#pragma unroll
      for (int mi = 0; mi < 4; mi++)
        af[mi] = *(const bf16x8*)&Al[wr * 64 + mi * 16 + lr][kk * 32 + lg * 8];
#pragma unroll
      for (int ni = 0; ni < 4; ni++)
        bfr[ni] = *(const bf16x8*)&Bl[wc * 64 + ni * 16 + lr][kk * 32 + lg * 8];
#pragma unroll
      for (int mi = 0; mi < 4; mi++)
#pragma unroll
        for (int ni = 0; ni < 4; ni++)
          acc[mi][ni] = __builtin_amdgcn_mfma_f32_16x16x32_bf16(af[mi], bfr[ni], acc[mi][ni], 0, 0, 0);
    }
    __syncthreads();
    if (t + 1 < nk) {
#pragma unroll
      for (int c = 0; c < 4; c++) {
        *(bf16x8*)&Al[c * 32 + srow][scol] = ra[c];
        *(bf16x8*)&Bl[c * 32 + srow][scol] = rb[c];
      }
      __syncthreads();
    }
  }

  // epilogue: D layout col=lane&15, row=(lane>>4)*4+r  [m89/m91 verified]
#pragma unroll
  for (int mi = 0; mi < 4; mi++) {
#pragma unroll
    for (int ni = 0; ni < 4; ni++) {
      int col = tn + wc * 64 + ni * 16 + lr;
#pragma unroll
      for (int r = 0; r < 4; r++) {
        int row = tm + wr * 64 + mi * 16 + lg * 4 + r;
        store_c(C, (size_t)row * N + col, acc[mi][ni][r]);
      }
    }
  }
}

// ---------------- causal flash attention ----------------
// grid (S/64, H, B), 256 threads (4 waves), QB=64 (16 q-rows/wave), KVB=64.
__global__ __launch_bounds__(256) void attn_kernel(const u16* __restrict__ Q,
                                                   const u16* __restrict__ K,
                                                   const u16* __restrict__ Vt,
                                                   u16* __restrict__ ctx) {
  __shared__ u16 Kl[64][136];    // stride 272B
  __shared__ u16 Vl[128][72];    // Vt tile: rows=d, cols=kv
  __shared__ u16 Pl[4][16][72];  // per-wave P

  int tid = threadIdx.x;
  int lane = tid & 63, wave = tid >> 6;
  int lr = lane & 15, lg = lane >> 4;
  int qt = blockIdx.x, h = blockIdx.y, b = blockIdx.z;
  int q0 = qt * 64;
  int q0w = q0 + wave * 16;

  // Q fragments: A-operand, row = lr, k = ks*32 + lg*8 + j
  const u16* qbase = Q + (size_t)(b * S_LEN + q0w + lr) * DM + h * DKH;
  bf16x8 qf[4];
#pragma unroll
  for (int ks = 0; ks < 4; ks++) qf[ks] = *(const bf16x8*)(qbase + ks * 32 + lg * 8);

  f32x4 zero4 = {0.f, 0.f, 0.f, 0.f};
  f32x4 acc[8];
#pragma unroll
  for (int f = 0; f < 8; f++) acc[f] = zero4;
  float m_r[4], l_r[4];
#pragma unroll
  for (int r = 0; r < 4; r++) { m_r[r] = -1e30f; l_r[r] = 0.f; }

  const float SCALE = 0.08838834764831845f;  // 1/sqrt(128)

  int ntiles = qt + 1;
  for (int t = 0; t < ntiles; t++) {
    int kv0 = t * 64;
    // stage K tile: 64 rows x 128 cols
#pragma unroll
    for (int c = 0; c < 4; c++) {
      int idx = c * 256 + tid;
      int row = idx >> 4, col = (idx & 15) * 8;
      bf16x8 v = *(const bf16x8*)(K + (size_t)(b * S_LEN + kv0 + row) * DM + h * DKH + col);
      *(bf16x8*)&Kl[row][col] = v;
    }
    // stage Vt tile: 128 rows(d) x 64 cols(kv)
#pragma unroll
    for (int c = 0; c < 4; c++) {
      int idx = c * 256 + tid;
      int row = idx >> 3, col = (idx & 7) * 8;
      bf16x8 v = *(const bf16x8*)(Vt + (size_t)((b * NH + h) * DKH + row) * S_LEN + kv0 + col);
      *(bf16x8*)&Vl[row][col] = v;
    }
    __syncthreads();

    // S = Q K^T (per wave: 16 q-rows x 64 kv)
    f32x4 sf[4];
#pragma unroll
    for (int n = 0; n < 4; n++) sf[n] = zero4;
#pragma unroll
    for (int n = 0; n < 4; n++)
#pragma unroll
      for (int ks = 0; ks < 4; ks++) {
        bf16x8 kf = *(const bf16x8*)&Kl[n * 16 + lr][ks * 32 + lg * 8];
        sf[n] = __builtin_amdgcn_mfma_f32_16x16x32_bf16(qf[ks], kf, sf[n], 0, 0, 0);
      }

    // mask + scale
    float sv[4][4];
#pragma unroll
    for (int n = 0; n < 4; n++) {
      int colg = kv0 + n * 16 + lr;
#pragma unroll
      for (int r = 0; r < 4; r++) {
        int rowg = q0w + lg * 4 + r;
        float x = sf[n][r] * SCALE;
        sv[n][r] = (colg <= rowg) ? x : -1e30f;
      }
    }
    // online softmax (row state lives in lanes of same lg group)
    float mnew[4], sc[4];
#pragma unroll
    for (int r = 0; r < 4; r++) {
      float mx = fmaxf(fmaxf(sv[0][r], sv[1][r]), fmaxf(sv[2][r], sv[3][r]));
      mx = fmaxf(mx, __shfl_xor(mx, 1));
      mx = fmaxf(mx, __shfl_xor(mx, 2));
      mx = fmaxf(mx, __shfl_xor(mx, 4));
      mx = fmaxf(mx, __shfl_xor(mx, 8));
      mnew[r] = fmaxf(m_r[r], mx);
      sc[r] = __expf(m_r[r] - mnew[r]);
      m_r[r] = mnew[r];
    }
    float rs[4] = {0.f, 0.f, 0.f, 0.f};
#pragma unroll
    for (int n = 0; n < 4; n++) {
#pragma unroll
      for (int r = 0; r < 4; r++) {
        float p = __expf(sv[n][r] - mnew[r]);  // masked -> exp(-huge) = 0
        rs[r] += p;
        Pl[wave][lg * 4 + r][n * 16 + lr] = f2bf(p);
      }
    }
#pragma unroll
    for (int r = 0; r < 4; r++) {
      float s = rs[r];
      s += __shfl_xor(s, 1);
      s += __shfl_xor(s, 2);
      s += __shfl_xor(s, 4);
      s += __shfl_xor(s, 8);
      l_r[r] = l_r[r] * sc[r] + s;
    }
#pragma unroll
    for (int f = 0; f < 8; f++)
#pragma unroll
      for (int r = 0; r < 4; r++) acc[f][r] *= sc[r];

    // PV: ctx += P(16x64) * V(64x128); A=P from Pl, B from Vl (contiguous b128)
#pragma unroll
    for (int ks2 = 0; ks2 < 2; ks2++) {
      bf16x8 pf = *(const bf16x8*)&Pl[wave][lr][ks2 * 32 + lg * 8];
#pragma unroll
      for (int f = 0; f < 8; f++) {
        bf16x8 vf = *(const bf16x8*)&Vl[f * 16 + lr][ks2 * 32 + lg * 8];
        acc[f] = __builtin_amdgcn_mfma_f32_16x16x32_bf16(pf, vf, acc[f], 0, 0, 0);
      }
    }
    __syncthreads();
  }

  // epilogue: ctx[b, s, h, d] bf16
  float inv[4];
#pragma unroll
  for (int r = 0; r < 4; r++) inv[r] = 1.0f / l_r[r];
#pragma unroll
  for (int f = 0; f < 8; f++) {
    int colg = h * DKH + f * 16 + lr;
#pragma unroll
    for (int r = 0; r < 4; r++) {
      int rowg = b * S_LEN + q0w + lg * 4 + r;
      ctx[(size_t)rowg * DM + colg] = f2bf(acc[f][r] * inv[r]);
    }
  }
}

extern "C" void kernel_launch(void* const* d_in, const int* in_sizes, int n_in,
                              void* d_out, int out_size, void* d_ws, size_t ws_size,
                              hipStream_t stream) {
  const float* x = (const float*)d_in[0];
  const float* Wq = (const float*)d_in[1];
  const float* Wk = (const float*)d_in[2];
  const float* Wv = (const float*)d_in[3];
  const float* Wo = (const float*)d_in[4];
  float* out = (float*)d_out;

  char* ws = (char*)d_ws;
  size_t off = 0;
  auto alloc = [&](size_t bytes) -> char* {
    char* p = ws + off;
    off += (bytes + 255) & ~(size_t)255;
    return p;
  };
  u16* xb = (u16*)alloc((size_t)NROWS * DM * 2);     // also reused as ctx
  u16* wqb = (u16*)alloc((size_t)DM * DM * 2);
  u16* wkb = (u16*)alloc((size_t)DM * DM * 2);
  u16* wvb = (u16*)alloc((size_t)DM * DM * 2);
  u16* wob = (u16*)alloc((size_t)DM * DM * 2);
  u16* Qb = (u16*)alloc((size_t)NROWS * DM * 2);
  u16* Kb = (u16*)alloc((size_t)NROWS * DM * 2);
  u16* Vb = (u16*)alloc((size_t)NROWS * DM * 2);
  u16* Vtb = (u16*)alloc((size_t)NROWS * DM * 2);
  float* cost = (float*)alloc((size_t)S_LEN * 64 * 4);
  float* sint = (float*)alloc((size_t)S_LEN * 64 * 4);
  u16* ctx = xb;  // xb dead after V projection

  // casts
  {
    int n4 = NROWS * DM / 4;
    cast_kernel<<<(n4 + 255) / 256, 256, 0, stream>>>(x, xb, n4);
    int w4 = DM * DM / 4;
    cast_kernel<<<(w4 + 255) / 256, 256, 0, stream>>>(Wq, wqb, w4);
    cast_kernel<<<(w4 + 255) / 256, 256, 0, stream>>>(Wk, wkb, w4);
    cast_kernel<<<(w4 + 255) / 256, 256, 0, stream>>>(Wv, wvb, w4);
    cast_kernel<<<(w4 + 255) / 256, 256, 0, stream>>>(Wo, wob, w4);
  }
  rope_table_kernel<<<(S_LEN * 64 + 255) / 256, 256, 0, stream>>>(cost, sint);

  dim3 ggrid(DM / 128, NROWS / 128);
  gemm_bt_kernel<u16><<<ggrid, 256, 0, stream>>>(xb, wqb, Qb, NROWS, DM, DM);
  gemm_bt_kernel<u16><<<ggrid, 256, 0, stream>>>(xb, wkb, Kb, NROWS, DM, DM);
  gemm_bt_kernel<u16><<<ggrid, 256, 0, stream>>>(xb, wvb, Vb, NROWS, DM, DM);

  {
    int np = NROWS * 1024;
    rope_apply_kernel<<<(np + 255) / 256, 256, 0, stream>>>(Qb, cost, sint);
    rope_apply_kernel<<<(np + 255) / 256, 256, 0, stream>>>(Kb, cost, sint);
  }
  transpose_v_kernel<<<dim3(DKH / 32, S_LEN / 32, NB * NH), 256, 0, stream>>>(Vb, Vtb);

  attn_kernel<<<dim3(S_LEN / 64, NH, NB), 256, 0, stream>>>(Qb, Kb, Vtb, ctx);

  gemm_bt_kernel<float><<<ggrid, 256, 0, stream>>>(ctx, wob, out, NROWS, DM, DM);
}

// Round 2
// 477.759 us; speedup vs baseline: 1.0932x; 1.0932x over previous
//
#include <hip/hip_runtime.h>
#include <stdint.h>

#define S_LEN 2048
#define DM 2048
#define NH 16
#define DKH 128
#define NB 2
#define NROWS (NB * S_LEN)  // 4096

typedef unsigned short u16;
typedef __attribute__((ext_vector_type(8))) __bf16 bf16x8;
typedef __attribute__((ext_vector_type(4))) float f32x4;

__device__ __forceinline__ float bf2f(u16 u) {
  union { unsigned u; float f; } v; v.u = ((unsigned)u) << 16; return v.f;
}
__device__ __forceinline__ u16 f2bf(float f) {
  union { float f; unsigned u; } v; v.f = f;
  unsigned r = v.u + 0x7FFFu + ((v.u >> 16) & 1u);
  return (u16)(r >> 16);
}

// async global->LDS, 16B per lane. lds = WAVE-UNIFORM chunk base (HW adds lane*16);
// g = PER-LANE global address. C-style casts do the addrspacecast (CK idiom).
__device__ __forceinline__ void async_copy16(void* lds, const void* g) {
  __builtin_amdgcn_global_load_lds(
      (const __attribute__((address_space(1))) unsigned int*)g,
      (__attribute__((address_space(3))) unsigned int*)lds, 16, 0, 0);
}

// ---------------- elementwise cast fp32 -> bf16 (vectorized x4) ----------------
__global__ void cast_kernel(const float* __restrict__ in, u16* __restrict__ out, int n4) {
  int i = blockIdx.x * blockDim.x + threadIdx.x;
  if (i >= n4) return;
  float4 v = ((const float4*)in)[i];
  unsigned r0 = (unsigned)f2bf(v.x) | ((unsigned)f2bf(v.y) << 16);
  unsigned r1 = (unsigned)f2bf(v.z) | ((unsigned)f2bf(v.w) << 16);
  ((uint2*)out)[i] = make_uint2(r0, r1);
}

// ---------------- RoPE cos/sin table: [S][64] ----------------
__global__ void rope_table_kernel(float* __restrict__ cost, float* __restrict__ sint) {
  int idx = blockIdx.x * blockDim.x + threadIdx.x;
  if (idx >= S_LEN * 64) return;
  int s = idx >> 6, i = idx & 63;
  float inv = expf(-9.210340371976184f * (float)i * (1.0f / 64.0f));
  float fr = (float)s * inv;
  cost[idx] = cosf(fr);
  sint[idx] = sinf(fr);
}

// ---------------- RoPE apply, interleaved pairs, in-place on bf16 ----------------
__global__ void rope_apply_kernel(u16* __restrict__ T, const float* __restrict__ cost,
                                  const float* __restrict__ sint) {
  int p = blockIdx.x * blockDim.x + threadIdx.x;
  if (p >= NROWS * 1024) return;
  int row = p >> 10, ci = p & 1023;
  int i = ci & 63;
  int s = row & (S_LEN - 1);
  unsigned* addr = (unsigned*)(T + ((size_t)row * DM + ci * 2));
  unsigned v = *addr;
  float t1 = bf2f((u16)(v & 0xffff));
  float t2 = bf2f((u16)(v >> 16));
  float c = cost[s * 64 + i], sn = sint[s * 64 + i];
  float o1 = t1 * c - t2 * sn;
  float o2 = t1 * sn + t2 * c;
  *addr = (unsigned)f2bf(o1) | ((unsigned)f2bf(o2) << 16);
}

// ---------------- V transpose: (b,s,h,d) -> Vt[(b*16+h)*128 + d][s] ----------------
__global__ void transpose_v_kernel(const u16* __restrict__ V, u16* __restrict__ Vt) {
  __shared__ u16 tile[32][33];
  int bh = blockIdx.z;
  int b = bh >> 4, h = bh & 15;
  int s0 = blockIdx.y * 32, d0 = blockIdx.x * 32;
  int tx = threadIdx.x & 31, ty = threadIdx.x >> 5;
  for (int i = ty; i < 32; i += 8)
    tile[i][tx] = V[(size_t)(b * S_LEN + s0 + i) * DM + h * DKH + d0 + tx];
  __syncthreads();
  for (int i = ty; i < 32; i += 8)
    Vt[(size_t)(bh * DKH + d0 + i) * S_LEN + s0 + tx] = tile[tx][i];
}

// ---------------- GEMM C = A(MxK) * B(NxK)^T (m97 structure) ----------------
// 128x128 tile, BK=64, 4 waves, linear LDS [128][64], global_load_lds w16,
// 2 barriers per K-step. XCD-swizzled block id.
__device__ __forceinline__ void store_c(u16* C, size_t idx, float v) { C[idx] = f2bf(v); }
__device__ __forceinline__ void store_c(float* C, size_t idx, float v) { C[idx] = v; }

template <typename OutT>
__global__ __launch_bounds__(256) void gemm_bt_kernel(const u16* __restrict__ A,
                                                      const u16* __restrict__ B,
                                                      OutT* __restrict__ C,
                                                      int M, int N, int Kd) {
  __shared__ u16 Al[128 * 64];
  __shared__ u16 Bl[128 * 64];
  int tid = threadIdx.x;
  int lane = tid & 63, wave = tid >> 6;
  int lr = lane & 15, lg = lane >> 4;
  int wr = wave >> 1, wc = wave & 1;

  // bijective XCD swizzle (nwg % 8 == 0 for all our launches)
  int gx = gridDim.x, nwg = gx * gridDim.y;
  int bid = blockIdx.y * gx + blockIdx.x;
  int cpx = nwg >> 3;
  int swz = (bid & 7) * cpx + (bid >> 3);
  int tm = (swz / gx) * 128, tn = (swz % gx) * 128;

  int srow = lane >> 3;        // row within 8-row chunk
  int scol = (lane & 7) * 8;   // elements

  f32x4 zero4 = {0.f, 0.f, 0.f, 0.f};
  f32x4 acc[4][4];
  for (int i = 0; i < 4; i++)
    for (int j = 0; j < 4; j++) acc[i][j] = zero4;

  int nk = Kd >> 6;
  for (int t = 0; t < nk; t++) {
    const u16* Abase = A + (size_t)tm * Kd + t * 64;
    const u16* Bbase = B + (size_t)tn * Kd + t * 64;
#pragma unroll
    for (int c = 0; c < 4; c++) {
      int ch = wave * 4 + c;            // 0..15, 1KB chunk = 8 rows
      int row = ch * 8 + srow;
      async_copy16(&Al[ch * 512], Abase + (size_t)row * Kd + scol);
      async_copy16(&Bl[ch * 512], Bbase + (size_t)row * Kd + scol);
    }
    __syncthreads();  // drains vmcnt(0) then barrier
#pragma unroll
    for (int kk = 0; kk < 2; kk++) {
      bf16x8 af[4], bfr[4];
#pragma unroll
      for (int mi = 0; mi < 4; mi++)
        af[mi] = *(const bf16x8*)&Al[(wr * 64 + mi * 16 + lr) * 64 + kk * 32 + lg * 8];
#pragma unroll
      for (int ni = 0; ni < 4; ni++)
        bfr[ni] = *(const bf16x8*)&Bl[(wc * 64 + ni * 16 + lr) * 64 + kk * 32 + lg * 8];
#pragma unroll
      for (int mi = 0; mi < 4; mi++)
#pragma unroll
        for (int ni = 0; ni < 4; ni++)
          acc[mi][ni] = __builtin_amdgcn_mfma_f32_16x16x32_bf16(af[mi], bfr[ni], acc[mi][ni], 0, 0, 0);
    }
    __syncthreads();
  }

#pragma unroll
  for (int mi = 0; mi < 4; mi++) {
#pragma unroll
    for (int ni = 0; ni < 4; ni++) {
      int col = tn + wc * 64 + ni * 16 + lr;
#pragma unroll
      for (int r = 0; r < 4; r++) {
        int row = tm + wr * 64 + mi * 16 + lg * 4 + r;
        store_c(C, (size_t)row * N + col, acc[mi][ni][r]);
      }
    }
  }
}

// ---------------- causal flash attention ----------------
// QB=128 (4 waves x 32 q-rows), KVB=64. K/V via global_load_lds with
// pre-swizzled source + XOR-swizzled reads (conflict-free ds_read_b128).
// Raw-units online softmax w/ deferred-max rescale. Longest-first qt order.
__device__ __forceinline__ int kidx(int row, int colb) {  // Kl [64][128], row stride 256B
  return ((row << 8) + (colb ^ ((row & 7) << 4))) >> 1;
}
__device__ __forceinline__ int vidx(int row, int colb) {  // Vl [128][64], row stride 128B
  return ((row << 7) + (colb ^ ((row & 7) << 4))) >> 1;
}

__global__ __launch_bounds__(256) void attn_kernel(const u16* __restrict__ Q,
                                                   const u16* __restrict__ K,
                                                   const u16* __restrict__ Vt,
                                                   u16* __restrict__ ctx) {
  __shared__ u16 Kl[64 * 128];     // 16KB, swizzled content
  __shared__ u16 Vl[128 * 64];     // 16KB, swizzled content
  __shared__ u16 Pl[4][32][72];    // 18KB, per-wave P

  int tid = threadIdx.x;
  int lane = tid & 63, wave = tid >> 6;
  int lr = lane & 15, lg = lane >> 4;
  int qt = (gridDim.x - 1) - blockIdx.x;  // longest-first
  int h = blockIdx.y, b = blockIdx.z;
  int q0 = qt * 128;
  int q0w = q0 + wave * 32;

  // Q fragments (A-operand): rows q0w + mf*16 + lr, k = ks*32+lg*8
  bf16x8 qf[2][4];
#pragma unroll
  for (int mf = 0; mf < 2; mf++) {
    const u16* qbase = Q + (size_t)(b * S_LEN + q0w + mf * 16 + lr) * DM + h * DKH;
#pragma unroll
    for (int ks = 0; ks < 4; ks++) qf[mf][ks] = *(const bf16x8*)(qbase + ks * 32 + lg * 8);
  }

  f32x4 zero4 = {0.f, 0.f, 0.f, 0.f};
  f32x4 acc[2][8];
#pragma unroll
  for (int mf = 0; mf < 2; mf++)
#pragma unroll
    for (int f = 0; f < 8; f++) acc[mf][f] = zero4;
  float m_r[2][4], l_r[2][4];
#pragma unroll
  for (int mf = 0; mf < 2; mf++)
#pragma unroll
    for (int r = 0; r < 4; r++) { m_r[mf][r] = -3.0e38f; l_r[mf][r] = 0.f; }

  const float SCALE = 0.08838834764831845f;  // 1/sqrt(128)
  const float RTHR = 64.0f;                  // defer-max threshold (raw units; *SCALE ~ 5.7)

  // staging geometry (per wave: 4 K-chunks + 4 V-chunks of 1KB)
  int krow_in = lane >> 4;            // + ch*4
  int kcolb = (lane & 15) * 16;       // linear dest byte within row
  int vrow_in = lane >> 3;            // + ch*8
  int vcolb = (lane & 7) * 16;

  const u16* Kbh = K + (size_t)b * S_LEN * DM + h * DKH;
  const u16* Vbh = Vt + (size_t)(b * NH + h) * DKH * S_LEN;

  int ntiles = 2 * qt + 2;
  for (int t = 0; t < ntiles; t++) {
    int kv0 = t * 64;
    // ---- stage K,V via global_load_lds, source pre-swizzled ----
#pragma unroll
    for (int c = 0; c < 4; c++) {
      int ch = wave * 4 + c;
      int krow = ch * 4 + krow_in;
      int ksrc = kcolb ^ ((krow & 7) << 4);
      async_copy16(&Kl[ch * 512], Kbh + (size_t)(kv0 + krow) * DM + (ksrc >> 1));
      int vrow = ch * 8 + vrow_in;
      int vsrc = vcolb ^ ((vrow & 7) << 4);
      async_copy16(&Vl[ch * 512], Vbh + (size_t)vrow * S_LEN + kv0 + (vsrc >> 1));
    }
    __syncthreads();  // vmcnt(0) drain + barrier

    if (kv0 <= q0w + 31) {  // wave-uniform: skip tiles fully above diagonal
      bool need_mask = (kv0 + 63 > q0w);

      // ---- S = Q K^T ----
      f32x4 sf[2][4];
#pragma unroll
      for (int mf = 0; mf < 2; mf++)
#pragma unroll
        for (int n = 0; n < 4; n++) sf[mf][n] = zero4;
#pragma unroll
      for (int n = 0; n < 4; n++)
#pragma unroll
        for (int ks = 0; ks < 4; ks++) {
          bf16x8 kf = *(const bf16x8*)&Kl[kidx(n * 16 + lr, ks * 64 + lg * 16)];
#pragma unroll
          for (int mf = 0; mf < 2; mf++)
            sf[mf][n] = __builtin_amdgcn_mfma_f32_16x16x32_bf16(qf[mf][ks], kf, sf[mf][n], 0, 0, 0);
        }

      // ---- mask + row max (raw units) ----
      float sv[2][4][4];
      float mx[2][4];
#pragma unroll
      for (int mf = 0; mf < 2; mf++) {
#pragma unroll
        for (int r = 0; r < 4; r++) mx[mf][r] = -3.0e38f;
#pragma unroll
        for (int n = 0; n < 4; n++) {
          int colg = kv0 + n * 16 + lr;
#pragma unroll
          for (int r = 0; r < 4; r++) {
            float x = sf[mf][n][r];
            if (need_mask) {
              int rowg = q0w + mf * 16 + lg * 4 + r;
              x = (colg <= rowg) ? x : -3.0e38f;
            }
            sv[mf][n][r] = x;
            mx[mf][r] = fmaxf(mx[mf][r], x);
          }
        }
#pragma unroll
        for (int r = 0; r < 4; r++) {
          float v = mx[mf][r];
          v = fmaxf(v, __shfl_xor(v, 1));
          v = fmaxf(v, __shfl_xor(v, 2));
          v = fmaxf(v, __shfl_xor(v, 4));
          v = fmaxf(v, __shfl_xor(v, 8));
          mx[mf][r] = v;
        }
      }

      // ---- deferred-max rescale ----
      bool need = false;
#pragma unroll
      for (int mf = 0; mf < 2; mf++)
#pragma unroll
        for (int r = 0; r < 4; r++) need |= (mx[mf][r] > m_r[mf][r] + RTHR);
      if (__any(need)) {
#pragma unroll
        for (int mf = 0; mf < 2; mf++)
#pragma unroll
          for (int r = 0; r < 4; r++) {
            float mnew = fmaxf(m_r[mf][r], mx[mf][r]);
            float sc = __expf((m_r[mf][r] - mnew) * SCALE);
            m_r[mf][r] = mnew;
            l_r[mf][r] *= sc;
#pragma unroll
            for (int f = 0; f < 8; f++) acc[mf][f][r] *= sc;
          }
      }

      // ---- P = exp((S - m)*SCALE), store to LDS, accumulate l ----
#pragma unroll
      for (int mf = 0; mf < 2; mf++) {
        float rs[4] = {0.f, 0.f, 0.f, 0.f};
#pragma unroll
        for (int n = 0; n < 4; n++)
#pragma unroll
          for (int r = 0; r < 4; r++) {
            float p = __expf((sv[mf][n][r] - m_r[mf][r]) * SCALE);
            rs[r] += p;
            Pl[wave][mf * 16 + lg * 4 + r][n * 16 + lr] = f2bf(p);
          }
#pragma unroll
        for (int r = 0; r < 4; r++) {
          float s = rs[r];
          s += __shfl_xor(s, 1);
          s += __shfl_xor(s, 2);
          s += __shfl_xor(s, 4);
          s += __shfl_xor(s, 8);
          l_r[mf][r] += s;
        }
      }

      // ---- PV: ctx += P(32x64) * V(64x128) ----
      bf16x8 pf[2][2];
#pragma unroll
      for (int mf = 0; mf < 2; mf++)
#pragma unroll
        for (int ks2 = 0; ks2 < 2; ks2++)
          pf[mf][ks2] = *(const bf16x8*)&Pl[wave][mf * 16 + lr][ks2 * 32 + lg * 8];
#pragma unroll
      for (int f = 0; f < 8; f++)
#pragma unroll
        for (int ks2 = 0; ks2 < 2; ks2++) {
          bf16x8 vf = *(const bf16x8*)&Vl[vidx(f * 16 + lr, ks2 * 64 + lg * 16)];
#pragma unroll
          for (int mf = 0; mf < 2; mf++)
            acc[mf][f] = __builtin_amdgcn_mfma_f32_16x16x32_bf16(pf[mf][ks2], vf, acc[mf][f], 0, 0, 0);
        }
    }
    __syncthreads();  // protect LDS before next stage
  }

  // ---- epilogue ----
#pragma unroll
  for (int mf = 0; mf < 2; mf++) {
    float inv[4];
#pragma unroll
    for (int r = 0; r < 4; r++) inv[r] = 1.0f / l_r[mf][r];
#pragma unroll
    for (int f = 0; f < 8; f++) {
      int colg = h * DKH + f * 16 + lr;
#pragma unroll
      for (int r = 0; r < 4; r++) {
        int rowg = b * S_LEN + q0w + mf * 16 + lg * 4 + r;
        ctx[(size_t)rowg * DM + colg] = f2bf(acc[mf][f][r] * inv[r]);
      }
    }
  }
}

extern "C" void kernel_launch(void* const* d_in, const int* in_sizes, int n_in,
                              void* d_out, int out_size, void* d_ws, size_t ws_size,
                              hipStream_t stream) {
  const float* x = (const float*)d_in[0];
  const float* Wq = (const float*)d_in[1];
  const float* Wk = (const float*)d_in[2];
  const float* Wv = (const float*)d_in[3];
  const float* Wo = (const float*)d_in[4];
  float* out = (float*)d_out;

  char* ws = (char*)d_ws;
  size_t off = 0;
  auto alloc = [&](size_t bytes) -> char* {
    char* p = ws + off;
    off += (bytes + 255) & ~(size_t)255;
    return p;
  };
  u16* xb = (u16*)alloc((size_t)NROWS * DM * 2);  // reused as ctx
  u16* wqb = (u16*)alloc((size_t)DM * DM * 2);
  u16* wkb = (u16*)alloc((size_t)DM * DM * 2);
  u16* wvb = (u16*)alloc((size_t)DM * DM * 2);
  u16* wob = (u16*)alloc((size_t)DM * DM * 2);
  u16* Qb = (u16*)alloc((size_t)NROWS * DM * 2);
  u16* Kb = (u16*)alloc((size_t)NROWS * DM * 2);
  u16* Vb = (u16*)alloc((size_t)NROWS * DM * 2);
  u16* Vtb = (u16*)alloc((size_t)NROWS * DM * 2);
  float* cost = (float*)alloc((size_t)S_LEN * 64 * 4);
  float* sint = (float*)alloc((size_t)S_LEN * 64 * 4);
  u16* ctx = xb;

  {
    int n4 = NROWS * DM / 4;
    cast_kernel<<<(n4 + 255) / 256, 256, 0, stream>>>(x, xb, n4);
    int w4 = DM * DM / 4;
    cast_kernel<<<(w4 + 255) / 256, 256, 0, stream>>>(Wq, wqb, w4);
    cast_kernel<<<(w4 + 255) / 256, 256, 0, stream>>>(Wk, wkb, w4);
    cast_kernel<<<(w4 + 255) / 256, 256, 0, stream>>>(Wv, wvb, w4);
    cast_kernel<<<(w4 + 255) / 256, 256, 0, stream>>>(Wo, wob, w4);
  }
  rope_table_kernel<<<(S_LEN * 64 + 255) / 256, 256, 0, stream>>>(cost, sint);

  dim3 ggrid(DM / 128, NROWS / 128);
  gemm_bt_kernel<u16><<<ggrid, 256, 0, stream>>>(xb, wqb, Qb, NROWS, DM, DM);
  gemm_bt_kernel<u16><<<ggrid, 256, 0, stream>>>(xb, wkb, Kb, NROWS, DM, DM);
  gemm_bt_kernel<u16><<<ggrid, 256, 0, stream>>>(xb, wvb, Vb, NROWS, DM, DM);

  {
    int np = NROWS * 1024;
    rope_apply_kernel<<<(np + 255) / 256, 256, 0, stream>>>(Qb, cost, sint);
    rope_apply_kernel<<<(np + 255) / 256, 256, 0, stream>>>(Kb, cost, sint);
  }
  transpose_v_kernel<<<dim3(DKH / 32, S_LEN / 32, NB * NH), 256, 0, stream>>>(Vb, Vtb);

  attn_kernel<<<dim3(S_LEN / 128, NH, NB), 256, 0, stream>>>(Qb, Kb, Vtb, ctx);

  gemm_bt_kernel<float><<<ggrid, 256, 0, stream>>>(ctx, wob, out, NROWS, DM, DM);
}

// Round 3
// 341.376 us; speedup vs baseline: 1.5300x; 1.3995x over previous
//
#include <hip/hip_runtime.h>
#include <stdint.h>

#define S_LEN 2048
#define DM 2048
#define NH 16
#define DKH 128
#define NB 2
#define NROWS (NB * S_LEN)  // 4096

typedef unsigned short u16;
typedef __attribute__((ext_vector_type(8))) __bf16 bf16x8;
typedef __attribute__((ext_vector_type(4))) float f32x4;

__device__ __forceinline__ float bf2f(u16 u) {
  union { unsigned u; float f; } v; v.u = ((unsigned)u) << 16; return v.f;
}
__device__ __forceinline__ u16 f2bf(float f) {
  union { float f; unsigned u; } v; v.f = f;
  unsigned r = v.u + 0x7FFFu + ((v.u >> 16) & 1u);
  return (u16)(r >> 16);
}

// async global->LDS, 16B per lane. lds = WAVE-UNIFORM chunk base (HW adds lane*16);
// g = PER-LANE global address.
__device__ __forceinline__ void async_copy16(void* lds, const void* g) {
  __builtin_amdgcn_global_load_lds(
      (const __attribute__((address_space(1))) unsigned int*)g,
      (__attribute__((address_space(3))) unsigned int*)lds, 16, 0, 0);
}

// ---------------- elementwise cast fp32 -> bf16 (vectorized x4) ----------------
__global__ void cast_kernel(const float* __restrict__ in, u16* __restrict__ out, int n4) {
  int i = blockIdx.x * blockDim.x + threadIdx.x;
  if (i >= n4) return;
  float4 v = ((const float4*)in)[i];
  unsigned r0 = (unsigned)f2bf(v.x) | ((unsigned)f2bf(v.y) << 16);
  unsigned r1 = (unsigned)f2bf(v.z) | ((unsigned)f2bf(v.w) << 16);
  ((uint2*)out)[i] = make_uint2(r0, r1);
}

// ---------------- RoPE cos/sin table: [S][64] ----------------
__global__ void rope_table_kernel(float* __restrict__ cost, float* __restrict__ sint) {
  int idx = blockIdx.x * blockDim.x + threadIdx.x;
  if (idx >= S_LEN * 64) return;
  int s = idx >> 6, i = idx & 63;
  float inv = expf(-9.210340371976184f * (float)i * (1.0f / 64.0f));
  float fr = (float)s * inv;
  cost[idx] = cosf(fr);
  sint[idx] = sinf(fr);
}

// ---------------- RoPE apply, interleaved pairs, in-place on bf16 ----------------
__global__ void rope_apply_kernel(u16* __restrict__ T, const float* __restrict__ cost,
                                  const float* __restrict__ sint) {
  int p = blockIdx.x * blockDim.x + threadIdx.x;
  if (p >= NROWS * 1024) return;
  int row = p >> 10, ci = p & 1023;
  int i = ci & 63;
  int s = row & (S_LEN - 1);
  unsigned* addr = (unsigned*)(T + ((size_t)row * DM + ci * 2));
  unsigned v = *addr;
  float t1 = bf2f((u16)(v & 0xffff));
  float t2 = bf2f((u16)(v >> 16));
  float c = cost[s * 64 + i], sn = sint[s * 64 + i];
  float o1 = t1 * c - t2 * sn;
  float o2 = t1 * sn + t2 * c;
  *addr = (unsigned)f2bf(o1) | ((unsigned)f2bf(o2) << 16);
}

// ---------------- GEMM C = A(MxK) * B(NxK)^T (m97 structure) ----------------
// 128x128 tile, BK=64, 4 waves, linear LDS, global_load_lds w16, XCD swizzle.
// EPI: 0 = row-major store (OutT), 1 = V-transpose store to Vt layout (u16).
__device__ __forceinline__ void store_c(u16* C, size_t idx, float v) { C[idx] = f2bf(v); }
__device__ __forceinline__ void store_c(float* C, size_t idx, float v) { C[idx] = v; }

template <typename OutT, int EPI>
__global__ __launch_bounds__(256) void gemm_bt_kernel(const u16* __restrict__ A,
                                                      const u16* __restrict__ B,
                                                      OutT* __restrict__ C,
                                                      int M, int N, int Kd) {
  __shared__ u16 Al[128 * 64];
  __shared__ u16 Bl[128 * 64];
  int tid = threadIdx.x;
  int lane = tid & 63, wave = tid >> 6;
  int lr = lane & 15, lg = lane >> 4;
  int wr = wave >> 1, wc = wave & 1;

  int gx = gridDim.x, nwg = gx * gridDim.y;
  int bid = blockIdx.y * gx + blockIdx.x;
  int cpx = nwg >> 3;
  int swz = (bid & 7) * cpx + (bid >> 3);
  int tm = (swz / gx) * 128, tn = (swz % gx) * 128;

  int srow = lane >> 3;
  int scol = (lane & 7) * 8;

  f32x4 zero4 = {0.f, 0.f, 0.f, 0.f};
  f32x4 acc[4][4];
  for (int i = 0; i < 4; i++)
    for (int j = 0; j < 4; j++) acc[i][j] = zero4;

  int nk = Kd >> 6;
  for (int t = 0; t < nk; t++) {
    const u16* Abase = A + (size_t)tm * Kd + t * 64;
    const u16* Bbase = B + (size_t)tn * Kd + t * 64;
#pragma unroll
    for (int c = 0; c < 4; c++) {
      int ch = wave * 4 + c;
      int row = ch * 8 + srow;
      async_copy16(&Al[ch * 512], Abase + (size_t)row * Kd + scol);
      async_copy16(&Bl[ch * 512], Bbase + (size_t)row * Kd + scol);
    }
    __syncthreads();
#pragma unroll
    for (int kk = 0; kk < 2; kk++) {
      bf16x8 af[4], bfr[4];
#pragma unroll
      for (int mi = 0; mi < 4; mi++)
        af[mi] = *(const bf16x8*)&Al[(wr * 64 + mi * 16 + lr) * 64 + kk * 32 + lg * 8];
#pragma unroll
      for (int ni = 0; ni < 4; ni++)
        bfr[ni] = *(const bf16x8*)&Bl[(wc * 64 + ni * 16 + lr) * 64 + kk * 32 + lg * 8];
#pragma unroll
      for (int mi = 0; mi < 4; mi++)
#pragma unroll
        for (int ni = 0; ni < 4; ni++)
          acc[mi][ni] = __builtin_amdgcn_mfma_f32_16x16x32_bf16(af[mi], bfr[ni], acc[mi][ni], 0, 0, 0);
    }
    __syncthreads();
  }

#pragma unroll
  for (int mi = 0; mi < 4; mi++) {
#pragma unroll
    for (int ni = 0; ni < 4; ni++) {
      int col = tn + wc * 64 + ni * 16 + lr;
      if constexpr (EPI == 1) {
        // Vt[(b*16+h)*128 + d][s], 4 consecutive s -> one 8B store
        int row0 = tm + wr * 64 + mi * 16 + lg * 4;
        size_t base = ((size_t)((row0 >> 11) * 16 + (col >> 7)) * 128 + (col & 127)) * S_LEN
                      + (row0 & (S_LEN - 1));
        unsigned w0 = (unsigned)f2bf(acc[mi][ni][0]) | ((unsigned)f2bf(acc[mi][ni][1]) << 16);
        unsigned w1 = (unsigned)f2bf(acc[mi][ni][2]) | ((unsigned)f2bf(acc[mi][ni][3]) << 16);
        *(uint2*)((u16*)C + base) = make_uint2(w0, w1);
      } else {
#pragma unroll
        for (int r = 0; r < 4; r++) {
          int row = tm + wr * 64 + mi * 16 + lg * 4 + r;
          store_c(C, (size_t)row * N + col, acc[mi][ni][r]);
        }
      }
    }
  }
}

// ---------------- causal flash attention (swapped-QK, P in registers) ----------------
// 4 waves, QB=128 (32 q-rows/wave as mf=0,1), KVB=64, double-buffered K/V LDS.
// K rows stored permuted: LDS row' holds global kv = phi(row'), so the swapped
// QK^T output (lane holds S[kv=phi(kf*16+lg*4+r)][q=mf*16+lr]) gives each lane
// kv = (kf>>1)*32 + lg*8 + (kf&1)*4 + r  -- exactly the PV A-fragment elements.
__device__ __forceinline__ int kidx(int row, int colb) {  // Kl [64][128] u16, row stride 256B
  return ((row << 8) + (colb ^ ((row & 7) << 4))) >> 1;
}
__device__ __forceinline__ int vidx(int row, int colb) {  // Vl [128][64] u16, row stride 128B
  return ((row << 7) + (colb ^ ((row & 7) << 4))) >> 1;
}

__global__ __launch_bounds__(256, 2) void attn_kernel(const u16* __restrict__ Q,
                                                      const u16* __restrict__ K,
                                                      const u16* __restrict__ Vt,
                                                      u16* __restrict__ ctx) {
  __shared__ u16 Kl[2][64 * 128];   // 32KB, swizzled + row-permuted content
  __shared__ u16 Vl[2][128 * 64];   // 32KB, swizzled content

  int tid = threadIdx.x;
  int lane = tid & 63, wave = tid >> 6;
  int lr = lane & 15, lg = lane >> 4;
  int bh = blockIdx.x;
  int b = bh >> 4, h = bh & 15;
  int qt = (gridDim.y - 1) - blockIdx.y;  // longest blocks dispatch first, device-wide
  int q0 = qt * 128;
  int q0w = q0 + wave * 32;

  // Q fragments (B-operand): q = q0w + mf*16 + lr, k-slice ks*32 + lg*8
  bf16x8 qf[2][4];
#pragma unroll
  for (int mf = 0; mf < 2; mf++) {
    const u16* qbase = Q + (size_t)(b * S_LEN + q0w + mf * 16 + lr) * DM + h * DKH;
#pragma unroll
    for (int ks = 0; ks < 4; ks++) qf[mf][ks] = *(const bf16x8*)(qbase + ks * 32 + lg * 8);
  }

  f32x4 zero4 = {0.f, 0.f, 0.f, 0.f};
  f32x4 acc[2][8];
#pragma unroll
  for (int mf = 0; mf < 2; mf++)
#pragma unroll
    for (int f = 0; f < 8; f++) acc[mf][f] = zero4;
  float m_r[2], l_r[2];
#pragma unroll
  for (int mf = 0; mf < 2; mf++) { m_r[mf] = -3.0e38f; l_r[mf] = 0.f; }

  const float SL2E = 1.4426950408889634f * 0.08838834764831845f;  // log2(e)/sqrt(128)
  const float RTHR = 64.0f;  // defer-max threshold, raw score units

  const u16* Kbh = K + (size_t)b * S_LEN * DM + h * DKH;
  const u16* Vbh = Vt + (size_t)(b * NH + h) * DKH * S_LEN;

  // stage one 64-kv tile into buffer `buf`
  auto stage = [&](int buf, int kv0s) {
#pragma unroll
    for (int c = 0; c < 4; c++) {
      int ch = wave * 4 + c;                       // 0..15
      int krow = ch * 4 + (lane >> 4);             // LDS K row 0..63
      // phi: LDS row -> global kv (bit permutation b4->b2, b3b2->b4b3)
      int kphi = (krow & 0x23) | ((krow & 0x10) >> 2) | ((krow & 0x0C) << 1);
      int kcb = ((((lane & 15) << 4) ^ ((krow & 7) << 4)) >> 1);
      async_copy16(&Kl[buf][ch * 512], Kbh + (size_t)(kv0s + kphi) * DM + kcb);
      int vrow = ch * 8 + (lane >> 3);             // LDS V row (=d) 0..127
      int vcb = ((((lane & 7) << 4) ^ ((vrow & 7) << 4)) >> 1);
      async_copy16(&Vl[buf][ch * 512], Vbh + (size_t)vrow * S_LEN + kv0s + vcb);
    }
  };

  int ntiles = 2 * qt + 2;
  stage(0, 0);
  __syncthreads();
  int cur = 0;

  for (int t = 0; t < ntiles; t++) {
    int kv0 = t * 64;
    if (t + 1 < ntiles) stage(cur ^ 1, (t + 1) * 64);

    if (kv0 <= q0w + 31) {  // wave-uniform causal skip
      bool need_mask = (kv0 + 63 > q0w);

      // ---- S^T = K Q^T : sf[kf][mf], lane holds S[kv=phi(kf*16+lg*4+r)][q=mf*16+lr]
      f32x4 sf[4][2];
#pragma unroll
      for (int kf = 0; kf < 4; kf++)
#pragma unroll
        for (int mf = 0; mf < 2; mf++) sf[kf][mf] = zero4;
      __builtin_amdgcn_s_setprio(1);
#pragma unroll
      for (int ks = 0; ks < 4; ks++)
#pragma unroll
        for (int kf = 0; kf < 4; kf++) {
          bf16x8 kfrag = *(const bf16x8*)&Kl[cur][kidx(kf * 16 + lr, ks * 64 + lg * 16)];
          sf[kf][0] = __builtin_amdgcn_mfma_f32_16x16x32_bf16(kfrag, qf[0][ks], sf[kf][0], 0, 0, 0);
          sf[kf][1] = __builtin_amdgcn_mfma_f32_16x16x32_bf16(kfrag, qf[1][ks], sf[kf][1], 0, 0, 0);
        }
      __builtin_amdgcn_s_setprio(0);

      // ---- mask + in-lane row max (q = mf*16+lr is lane-local) ----
      float sv[2][4][4];
      float mx[2];
#pragma unroll
      for (int mf = 0; mf < 2; mf++) {
        int qg = q0w + mf * 16 + lr;
        mx[mf] = -3.0e38f;
#pragma unroll
        for (int kf = 0; kf < 4; kf++) {
          int kvb = kv0 + (kf >> 1) * 32 + (kf & 1) * 4 + lg * 8;
#pragma unroll
          for (int r = 0; r < 4; r++) {
            float x = sf[kf][mf][r];
            if (need_mask) x = (kvb + r <= qg) ? x : -3.0e38f;
            sv[mf][kf][r] = x;
            mx[mf] = fmaxf(mx[mf], x);
          }
        }
        // replicate stats across the 4 lg-lanes sharing lr
        mx[mf] = fmaxf(mx[mf], __shfl_xor(mx[mf], 16));
        mx[mf] = fmaxf(mx[mf], __shfl_xor(mx[mf], 32));
      }

      // ---- deferred-max rescale ----
      bool need = (mx[0] > m_r[0] + RTHR) | (mx[1] > m_r[1] + RTHR);
      if (__any(need)) {
        float scs[2];
#pragma unroll
        for (int mf = 0; mf < 2; mf++) {
          float mnew = fmaxf(m_r[mf], mx[mf]);
          scs[mf] = __builtin_amdgcn_exp2f((m_r[mf] - mnew) * SL2E);
          m_r[mf] = mnew;
          l_r[mf] *= scs[mf];
        }
        // acc element r has q-local lg*4+r; stat lives in lanes with lr == lg*4+r
#pragma unroll
        for (int mf = 0; mf < 2; mf++) {
#pragma unroll
          for (int r = 0; r < 4; r++) {
            float sa = __shfl(scs[mf], (lane & 0x30) | (lg * 4 + r));
#pragma unroll
            for (int f = 0; f < 8; f++) acc[mf][f][r] *= sa;
          }
        }
      }

      // ---- P = exp2((S-m)*SL2E) in-lane; accumulate l; pack PV A-fragments ----
      bf16x8 pf[2][2];
#pragma unroll
      for (int mf = 0; mf < 2; mf++) {
        float rs = 0.f;
#pragma unroll
        for (int kf = 0; kf < 4; kf++)
#pragma unroll
          for (int r = 0; r < 4; r++) {
            float p = __builtin_amdgcn_exp2f((sv[mf][kf][r] - m_r[mf]) * SL2E);
            sv[mf][kf][r] = p;
            rs += p;
          }
        rs += __shfl_xor(rs, 16);
        rs += __shfl_xor(rs, 32);
        l_r[mf] += rs;
#pragma unroll
        for (int ks2 = 0; ks2 < 2; ks2++) {
          bf16x8 t;
#pragma unroll
          for (int r = 0; r < 4; r++) {
            t[r] = (__bf16)sv[mf][2 * ks2][r];
            t[4 + r] = (__bf16)sv[mf][2 * ks2 + 1][r];
          }
          pf[mf][ks2] = t;
        }
      }

      // ---- PV: acc += P(32x64) * V^T(64x128) ----
      __builtin_amdgcn_s_setprio(1);
#pragma unroll
      for (int ks2 = 0; ks2 < 2; ks2++)
#pragma unroll
        for (int f = 0; f < 8; f++) {
          bf16x8 vf = *(const bf16x8*)&Vl[cur][vidx(f * 16 + lr, ks2 * 64 + lg * 16)];
          acc[0][f] = __builtin_amdgcn_mfma_f32_16x16x32_bf16(pf[0][ks2], vf, acc[0][f], 0, 0, 0);
          acc[1][f] = __builtin_amdgcn_mfma_f32_16x16x32_bf16(pf[1][ks2], vf, acc[1][f], 0, 0, 0);
        }
      __builtin_amdgcn_s_setprio(0);
    }
    __syncthreads();
    cur ^= 1;
  }

  // ---- epilogue: acc[mf][f][r] -> ctx[q0w+mf*16+lg*4+r][h*128+f*16+lr] ----
#pragma unroll
  for (int mf = 0; mf < 2; mf++) {
    float invl = 1.0f / l_r[mf];
#pragma unroll
    for (int r = 0; r < 4; r++) {
      float ia = __shfl(invl, (lane & 0x30) | (lg * 4 + r));
      int rowg = b * S_LEN + q0w + mf * 16 + lg * 4 + r;
#pragma unroll
      for (int f = 0; f < 8; f++) {
        int colg = h * DKH + f * 16 + lr;
        ctx[(size_t)rowg * DM + colg] = f2bf(acc[mf][f][r] * ia);
      }
    }
  }
}

extern "C" void kernel_launch(void* const* d_in, const int* in_sizes, int n_in,
                              void* d_out, int out_size, void* d_ws, size_t ws_size,
                              hipStream_t stream) {
  const float* x = (const float*)d_in[0];
  const float* Wq = (const float*)d_in[1];
  const float* Wk = (const float*)d_in[2];
  const float* Wv = (const float*)d_in[3];
  const float* Wo = (const float*)d_in[4];
  float* out = (float*)d_out;

  char* ws = (char*)d_ws;
  size_t off = 0;
  auto alloc = [&](size_t bytes) -> char* {
    char* p = ws + off;
    off += (bytes + 255) & ~(size_t)255;
    return p;
  };
  u16* xb = (u16*)alloc((size_t)NROWS * DM * 2);  // reused as ctx
  u16* wqb = (u16*)alloc((size_t)DM * DM * 2);
  u16* wkb = (u16*)alloc((size_t)DM * DM * 2);
  u16* wvb = (u16*)alloc((size_t)DM * DM * 2);
  u16* wob = (u16*)alloc((size_t)DM * DM * 2);
  u16* Qb = (u16*)alloc((size_t)NROWS * DM * 2);
  u16* Kb = (u16*)alloc((size_t)NROWS * DM * 2);
  u16* Vtb = (u16*)alloc((size_t)NROWS * DM * 2);
  float* cost = (float*)alloc((size_t)S_LEN * 64 * 4);
  float* sint = (float*)alloc((size_t)S_LEN * 64 * 4);
  u16* ctx = xb;

  {
    int n4 = NROWS * DM / 4;
    cast_kernel<<<(n4 + 255) / 256, 256, 0, stream>>>(x, xb, n4);
    int w4 = DM * DM / 4;
    cast_kernel<<<(w4 + 255) / 256, 256, 0, stream>>>(Wq, wqb, w4);
    cast_kernel<<<(w4 + 255) / 256, 256, 0, stream>>>(Wk, wkb, w4);
    cast_kernel<<<(w4 + 255) / 256, 256, 0, stream>>>(Wv, wvb, w4);
    cast_kernel<<<(w4 + 255) / 256, 256, 0, stream>>>(Wo, wob, w4);
  }
  rope_table_kernel<<<(S_LEN * 64 + 255) / 256, 256, 0, stream>>>(cost, sint);

  dim3 ggrid(DM / 128, NROWS / 128);
  gemm_bt_kernel<u16, 0><<<ggrid, 256, 0, stream>>>(xb, wqb, Qb, NROWS, DM, DM);
  gemm_bt_kernel<u16, 0><<<ggrid, 256, 0, stream>>>(xb, wkb, Kb, NROWS, DM, DM);
  gemm_bt_kernel<u16, 1><<<ggrid, 256, 0, stream>>>(xb, wvb, Vtb, NROWS, DM, DM);

  {
    int np = NROWS * 1024;
    rope_apply_kernel<<<(np + 255) / 256, 256, 0, stream>>>(Qb, cost, sint);
    rope_apply_kernel<<<(np + 255) / 256, 256, 0, stream>>>(Kb, cost, sint);
  }

  attn_kernel<<<dim3(NB * NH, S_LEN / 128), 256, 0, stream>>>(Qb, Kb, Vtb, ctx);

  gemm_bt_kernel<float, 0><<<ggrid, 256, 0, stream>>>(ctx, wob, out, NROWS, DM, DM);
}

// Round 4
// 298.307 us; speedup vs baseline: 1.7509x; 1.1444x over previous
//
#include <hip/hip_runtime.h>
#include <stdint.h>
#include <type_traits>

#define S_LEN 2048
#define DM 2048
#define NH 16
#define DKH 128
#define NB 2
#define NROWS (NB * S_LEN)  // 4096

typedef unsigned short u16;
typedef __attribute__((ext_vector_type(8))) __bf16 bf16x8;
typedef __attribute__((ext_vector_type(4))) float f32x4;

__device__ __forceinline__ float bf2f(u16 u) {
  union { unsigned u; float f; } v; v.u = ((unsigned)u) << 16; return v.f;
}
__device__ __forceinline__ u16 f2bf(float f) {
  union { float f; unsigned u; } v; v.f = f;
  unsigned r = v.u + 0x7FFFu + ((v.u >> 16) & 1u);
  return (u16)(r >> 16);
}

// async global->LDS, 16B per lane. lds = WAVE-UNIFORM chunk base (HW adds lane*16);
// g = PER-LANE global address.
__device__ __forceinline__ void async_copy16(void* lds, const void* g) {
  __builtin_amdgcn_global_load_lds(
      (const __attribute__((address_space(1))) unsigned int*)g,
      (__attribute__((address_space(3))) unsigned int*)lds, 16, 0, 0);
}

// ---------------- elementwise cast fp32 -> bf16 (vectorized x4) ----------------
__global__ void cast_kernel(const float* __restrict__ in, u16* __restrict__ out, int n4) {
  int i = blockIdx.x * blockDim.x + threadIdx.x;
  if (i >= n4) return;
  float4 v = ((const float4*)in)[i];
  unsigned r0 = (unsigned)f2bf(v.x) | ((unsigned)f2bf(v.y) << 16);
  unsigned r1 = (unsigned)f2bf(v.z) | ((unsigned)f2bf(v.w) << 16);
  ((uint2*)out)[i] = make_uint2(r0, r1);
}

// ---------------- RoPE cos/sin table: [S][64] ----------------
__global__ void rope_table_kernel(float* __restrict__ cost, float* __restrict__ sint) {
  int idx = blockIdx.x * blockDim.x + threadIdx.x;
  if (idx >= S_LEN * 64) return;
  int s = idx >> 6, i = idx & 63;
  float inv = expf(-9.210340371976184f * (float)i * (1.0f / 64.0f));
  float fr = (float)s * inv;
  cost[idx] = cosf(fr);
  sint[idx] = sinf(fr);
}

// ---------------- RoPE apply, interleaved pairs, in-place on bf16 ----------------
__global__ void rope_apply_kernel(u16* __restrict__ T, const float* __restrict__ cost,
                                  const float* __restrict__ sint) {
  int p = blockIdx.x * blockDim.x + threadIdx.x;
  if (p >= NROWS * 1024) return;
  int row = p >> 10, ci = p & 1023;
  int i = ci & 63;
  int s = row & (S_LEN - 1);
  unsigned* addr = (unsigned*)(T + ((size_t)row * DM + ci * 2));
  unsigned v = *addr;
  float t1 = bf2f((u16)(v & 0xffff));
  float t2 = bf2f((u16)(v >> 16));
  float c = cost[s * 64 + i], sn = sint[s * 64 + i];
  float o1 = t1 * c - t2 * sn;
  float o2 = t1 * sn + t2 * c;
  *addr = (unsigned)f2bf(o1) | ((unsigned)f2bf(o2) << 16);
}

// ================= 256x256 8-phase GEMM (T2+T3+T4+T5 template) =================
// C = A(MxK) * B(NxK)^T. BK=64, 8 waves (2M x 4N), per-wave 128x64 output.
// LDS 128KB: [A-even 32K][B-even 32K][A-odd 32K][B-odd 32K], each = top/bot 16K
// halves of 128 rows x 64 cols bf16, XOR-swizzled (byte ^= (row&7)<<4) via
// pre-swizzled global_load_lds source. Counted vmcnt(6) at phases 0/4 only.
// Stage slots per iter i (computing tiles 2i even-buf, 2i+1 odd-buf):
//   ph0: A-odd.top<-2i+1   ph1: A-odd.bot<-2i+1
//   ph2: B-even.top<-2i+2  ph3: B-even.bot<-2i+2
//   ph4: A-even.top<-2i+2  ph5: A-even.bot<-2i+2
//   ph6: B-odd.top<-2i+3   ph7: B-odd.bot<-2i+3
// EPI 0: single f32 row-major output (C0, stride N).
// EPI 2: QKV split: cols [0,2048)->C0 (bf16), [2048,4096)->C1 (bf16),
//        [4096,6144)->C2 transposed into Vt[(b*16+h)*128+d][s] (bf16).
#define LDS_AE 0
#define LDS_BE 32768
#define LDS_AO 65536
#define LDS_BO 98304

template <int EPI>
__global__ __launch_bounds__(512, 2) void gemm256_kernel(const u16* __restrict__ A,
                                                         const u16* __restrict__ B,
                                                         void* __restrict__ C0,
                                                         void* __restrict__ C1,
                                                         void* __restrict__ C2,
                                                         int M, int N, int Kd) {
  extern __shared__ char smem[];
  u16* lds = (u16*)smem;

  int tid = threadIdx.x;
  int lane = tid & 63, wave = tid >> 6;
  int lr = lane & 15, lg = lane >> 4;
  int wm = wave >> 2, wn = wave & 3;

  // bijective XCD swizzle (nwg % 8 == 0 for all launches here)
  int gx = gridDim.x, nwg = gx * gridDim.y;
  int bid = blockIdx.y * gx + blockIdx.x;
  int cpx = nwg >> 3;
  int swz = (bid & 7) * cpx + (bid >> 3);
  int tm = (swz / gx) * 256, tn = (swz % gx) * 256;

  // staging geometry: per stage() call each thread issues 2 gload_lds (16B).
  // chunk ch = l*8+wave covers LDS bytes [base+ch*1024,+1024) = rows [ch*8,ch*8+8).
  int srow_in = lane >> 3;                                  // 0..7
  int scolb = ((lane & 7) * 16) ^ ((lane >> 3) << 4);       // pre-swizzled src byte-col

  const u16* Arows = A + (size_t)tm * Kd;
  const u16* Brows = B + (size_t)tn * Kd;

  auto stage = [&](int halfBase, const u16* Grows, int rowOff, int kt) {
#pragma unroll
    for (int l = 0; l < 2; l++) {
      int ch = l * 8 + wave;
      async_copy16(lds + ((halfBase + ch * 1024) >> 1),
                   Grows + (size_t)(rowOff + ch * 8 + srow_in) * Kd + kt * 64 + (scolb >> 1));
    }
  };

  // read-address helpers (swizzled): row&7 == lr&7 for all frag reads
  int arow_b = lr * 128;                     // byte offset of row lr within a frag-row group
  int acolb[2];
#pragma unroll
  for (int ks = 0; ks < 2; ks++) acolb[ks] = (ks * 64 + lg * 16) ^ ((lr & 7) << 4);
  int aBaseW = wm * 16384;                               // A half per wave-M
  int bhrow_b = (wn >> 1) * 16384 + ((wn & 1) * 64 + lr) * 128;  // B half+row per wave-N

  f32x4 zero4 = {0.f, 0.f, 0.f, 0.f};
  f32x4 acc[8][4];
#pragma unroll
  for (int i = 0; i < 8; i++)
#pragma unroll
    for (int j = 0; j < 4; j++) acc[i][j] = zero4;

  bf16x8 bpre[4][2];
  bf16x8 af[2][2];

  auto loadB = [&](int bBase) {
#pragma unroll
    for (int nf = 0; nf < 4; nf++)
#pragma unroll
      for (int ks = 0; ks < 2; ks++)
        bpre[nf][ks] = *(const bf16x8*)&lds[(bBase + bhrow_b + nf * 2048 + acolb[ks]) >> 1];
  };
  auto readA = [&](int aBase, int q) {
#pragma unroll
    for (int dm = 0; dm < 2; dm++)
#pragma unroll
      for (int ks = 0; ks < 2; ks++)
        af[dm][ks] =
            *(const bf16x8*)&lds[(aBase + aBaseW + (2 * q + dm) * 2048 + arow_b + acolb[ks]) >> 1];
  };
  auto mfma16 = [&](auto qc) {
    constexpr int Q = decltype(qc)::value;
    __builtin_amdgcn_s_setprio(1);
#pragma unroll
    for (int dm = 0; dm < 2; dm++)
#pragma unroll
      for (int nf = 0; nf < 4; nf++)
#pragma unroll
        for (int ks = 0; ks < 2; ks++)
          acc[2 * Q + dm][nf] = __builtin_amdgcn_mfma_f32_16x16x32_bf16(
              af[dm][ks], bpre[nf][ks], acc[2 * Q + dm][nf], 0, 0, 0);
    __builtin_amdgcn_s_setprio(0);
  };

  int nk = Kd >> 6;        // 64-wide K tiles (32 here)
  int nIter = nk >> 1;     // 2 tiles per iteration

  // ---- prologue: tile0 A+B into even, tile1 B into odd (12 loads) ----
  stage(LDS_AE + 0, Arows, 0, 0);
  stage(LDS_AE + 16384, Arows, 128, 0);
  stage(LDS_BE + 0, Brows, 0, 0);
  stage(LDS_BE + 16384, Brows, 128, 0);
  stage(LDS_BO + 0, Brows, 0, 1);
  stage(LDS_BO + 16384, Brows, 128, 1);

  for (int i = 0; i < nIter; i++) {
    int tO = 2 * i + 1;
    int tE2 = 2 * i + 2; if (tE2 > nk - 1) tE2 = nk - 1;
    int tO2 = 2 * i + 3; if (tO2 > nk - 1) tO2 = nk - 1;

    // ---- ph0 ----
    stage(LDS_AO + 0, Arows, 0, tO);
    asm volatile("s_waitcnt vmcnt(6)" ::: "memory");
    __builtin_amdgcn_s_barrier();
    __builtin_amdgcn_sched_barrier(0);
    loadB(LDS_BE);
    readA(LDS_AE, 0);
    mfma16(std::integral_constant<int, 0>{});
    __builtin_amdgcn_s_barrier();
    // ---- ph1 ----
    readA(LDS_AE, 1);
    stage(LDS_AO + 16384, Arows, 128, tO);
    mfma16(std::integral_constant<int, 1>{});
    __builtin_amdgcn_s_barrier();
    // ---- ph2 ----
    readA(LDS_AE, 2);
    stage(LDS_BE + 0, Brows, 0, tE2);
    mfma16(std::integral_constant<int, 2>{});
    __builtin_amdgcn_s_barrier();
    // ---- ph3 ----
    readA(LDS_AE, 3);
    stage(LDS_BE + 16384, Brows, 128, tE2);
    mfma16(std::integral_constant<int, 3>{});
    __builtin_amdgcn_s_barrier();
    // ---- ph4 ----
    stage(LDS_AE + 0, Arows, 0, tE2);
    asm volatile("s_waitcnt vmcnt(6)" ::: "memory");
    __builtin_amdgcn_s_barrier();
    __builtin_amdgcn_sched_barrier(0);
    loadB(LDS_BO);
    readA(LDS_AO, 0);
    mfma16(std::integral_constant<int, 0>{});
    __builtin_amdgcn_s_barrier();
    // ---- ph5 ----
    readA(LDS_AO, 1);
    stage(LDS_AE + 16384, Arows, 128, tE2);
    mfma16(std::integral_constant<int, 1>{});
    __builtin_amdgcn_s_barrier();
    // ---- ph6 ----
    readA(LDS_AO, 2);
    stage(LDS_BO + 0, Brows, 0, tO2);
    mfma16(std::integral_constant<int, 2>{});
    __builtin_amdgcn_s_barrier();
    // ---- ph7 ----
    readA(LDS_AO, 3);
    stage(LDS_BO + 16384, Brows, 128, tO2);
    mfma16(std::integral_constant<int, 3>{});
    __builtin_amdgcn_s_barrier();
  }

  asm volatile("s_waitcnt vmcnt(0)" ::: "memory");  // drain dangling prefetches

  // ---- epilogue: row = tm + wm*128 + mf*16 + lg*4 + r; col = tn + wn*64 + nf*16 + lr ----
#pragma unroll
  for (int mf = 0; mf < 8; mf++) {
    int row = tm + wm * 128 + mf * 16 + lg * 4;
#pragma unroll
    for (int nf = 0; nf < 4; nf++) {
      int col = tn + wn * 64 + nf * 16 + lr;
      if constexpr (EPI == 0) {
        float* O = (float*)C0;
#pragma unroll
        for (int r = 0; r < 4; r++) O[(size_t)(row + r) * N + col] = acc[mf][nf][r];
      } else {
        int mat = col >> 11, lc = col & 2047;
        if (mat == 0) {
          u16* O = (u16*)C0;
#pragma unroll
          for (int r = 0; r < 4; r++) O[(size_t)(row + r) * 2048 + lc] = f2bf(acc[mf][nf][r]);
        } else if (mat == 1) {
          u16* O = (u16*)C1;
#pragma unroll
          for (int r = 0; r < 4; r++) O[(size_t)(row + r) * 2048 + lc] = f2bf(acc[mf][nf][r]);
        } else {
          u16* O = (u16*)C2;  // Vt[(b*16+h)*128 + d][s]
          int h = lc >> 7, d = lc & 127;
          int b = row >> 11, s = row & 2047;
          unsigned w0 = (unsigned)f2bf(acc[mf][nf][0]) | ((unsigned)f2bf(acc[mf][nf][1]) << 16);
          unsigned w1 = (unsigned)f2bf(acc[mf][nf][2]) | ((unsigned)f2bf(acc[mf][nf][3]) << 16);
          *(uint2*)(O + ((size_t)((b * 16 + h) * 128 + d) * 2048 + s)) = make_uint2(w0, w1);
        }
      }
    }
  }
}

// ---------------- causal flash attention (swapped-QK, P in registers) ----------------
__device__ __forceinline__ int kidx(int row, int colb) {  // Kl [64][128] u16
  return ((row << 8) + (colb ^ ((row & 7) << 4))) >> 1;
}
__device__ __forceinline__ int vidx(int row, int colb) {  // Vl [128][64] u16
  return ((row << 7) + (colb ^ ((row & 7) << 4))) >> 1;
}

__global__ __launch_bounds__(256, 2) void attn_kernel(const u16* __restrict__ Q,
                                                      const u16* __restrict__ K,
                                                      const u16* __restrict__ Vt,
                                                      u16* __restrict__ ctx) {
  __shared__ u16 Kl[2][64 * 128];
  __shared__ u16 Vl[2][128 * 64];

  int tid = threadIdx.x;
  int lane = tid & 63, wave = tid >> 6;
  int lr = lane & 15, lg = lane >> 4;
  int bh = blockIdx.x;
  int b = bh >> 4, h = bh & 15;
  int qt = (gridDim.y - 1) - blockIdx.y;
  int q0 = qt * 128;
  int q0w = q0 + wave * 32;

  bf16x8 qf[2][4];
#pragma unroll
  for (int mf = 0; mf < 2; mf++) {
    const u16* qbase = Q + (size_t)(b * S_LEN + q0w + mf * 16 + lr) * DM + h * DKH;
#pragma unroll
    for (int ks = 0; ks < 4; ks++) qf[mf][ks] = *(const bf16x8*)(qbase + ks * 32 + lg * 8);
  }

  f32x4 zero4 = {0.f, 0.f, 0.f, 0.f};
  f32x4 acc[2][8];
#pragma unroll
  for (int mf = 0; mf < 2; mf++)
#pragma unroll
    for (int f = 0; f < 8; f++) acc[mf][f] = zero4;
  float m_r[2], l_r[2];
#pragma unroll
  for (int mf = 0; mf < 2; mf++) { m_r[mf] = -3.0e38f; l_r[mf] = 0.f; }

  const float SL2E = 1.4426950408889634f * 0.08838834764831845f;
  const float RTHR = 64.0f;

  const u16* Kbh = K + (size_t)b * S_LEN * DM + h * DKH;
  const u16* Vbh = Vt + (size_t)(b * NH + h) * DKH * S_LEN;

  auto stage = [&](int buf, int kv0s) {
#pragma unroll
    for (int c = 0; c < 4; c++) {
      int ch = wave * 4 + c;
      int krow = ch * 4 + (lane >> 4);
      int kphi = (krow & 0x23) | ((krow & 0x10) >> 2) | ((krow & 0x0C) << 1);
      int kcb = ((((lane & 15) << 4) ^ ((krow & 7) << 4)) >> 1);
      async_copy16(&Kl[buf][ch * 512], Kbh + (size_t)(kv0s + kphi) * DM + kcb);
      int vrow = ch * 8 + (lane >> 3);
      int vcb = ((((lane & 7) << 4) ^ ((vrow & 7) << 4)) >> 1);
      async_copy16(&Vl[buf][ch * 512], Vbh + (size_t)vrow * S_LEN + kv0s + vcb);
    }
  };

  int ntiles = 2 * qt + 2;
  stage(0, 0);
  __syncthreads();
  int cur = 0;

  for (int t = 0; t < ntiles; t++) {
    int kv0 = t * 64;
    if (t + 1 < ntiles) stage(cur ^ 1, (t + 1) * 64);

    if (kv0 <= q0w + 31) {
      bool need_mask = (kv0 + 63 > q0w);

      f32x4 sf[4][2];
#pragma unroll
      for (int kf = 0; kf < 4; kf++)
#pragma unroll
        for (int mf = 0; mf < 2; mf++) sf[kf][mf] = zero4;
      __builtin_amdgcn_s_setprio(1);
#pragma unroll
      for (int ks = 0; ks < 4; ks++)
#pragma unroll
        for (int kf = 0; kf < 4; kf++) {
          bf16x8 kfrag = *(const bf16x8*)&Kl[cur][kidx(kf * 16 + lr, ks * 64 + lg * 16)];
          sf[kf][0] = __builtin_amdgcn_mfma_f32_16x16x32_bf16(kfrag, qf[0][ks], sf[kf][0], 0, 0, 0);
          sf[kf][1] = __builtin_amdgcn_mfma_f32_16x16x32_bf16(kfrag, qf[1][ks], sf[kf][1], 0, 0, 0);
        }
      __builtin_amdgcn_s_setprio(0);

      float sv[2][4][4];
      float mx[2];
#pragma unroll
      for (int mf = 0; mf < 2; mf++) {
        int qg = q0w + mf * 16 + lr;
        mx[mf] = -3.0e38f;
#pragma unroll
        for (int kf = 0; kf < 4; kf++) {
          int kvb = kv0 + (kf >> 1) * 32 + (kf & 1) * 4 + lg * 8;
#pragma unroll
          for (int r = 0; r < 4; r++) {
            float x = sf[kf][mf][r];
            if (need_mask) x = (kvb + r <= qg) ? x : -3.0e38f;
            sv[mf][kf][r] = x;
            mx[mf] = fmaxf(mx[mf], x);
          }
        }
        mx[mf] = fmaxf(mx[mf], __shfl_xor(mx[mf], 16));
        mx[mf] = fmaxf(mx[mf], __shfl_xor(mx[mf], 32));
      }

      bool need = (mx[0] > m_r[0] + RTHR) | (mx[1] > m_r[1] + RTHR);
      if (__any(need)) {
        float scs[2];
#pragma unroll
        for (int mf = 0; mf < 2; mf++) {
          float mnew = fmaxf(m_r[mf], mx[mf]);
          scs[mf] = __builtin_amdgcn_exp2f((m_r[mf] - mnew) * SL2E);
          m_r[mf] = mnew;
          l_r[mf] *= scs[mf];
        }
#pragma unroll
        for (int mf = 0; mf < 2; mf++) {
#pragma unroll
          for (int r = 0; r < 4; r++) {
            float sa = __shfl(scs[mf], (lane & 0x30) | (lg * 4 + r));
#pragma unroll
            for (int f = 0; f < 8; f++) acc[mf][f][r] *= sa;
          }
        }
      }

      bf16x8 pf[2][2];
#pragma unroll
      for (int mf = 0; mf < 2; mf++) {
        float rs = 0.f;
#pragma unroll
        for (int kf = 0; kf < 4; kf++)
#pragma unroll
          for (int r = 0; r < 4; r++) {
            float p = __builtin_amdgcn_exp2f((sv[mf][kf][r] - m_r[mf]) * SL2E);
            sv[mf][kf][r] = p;
            rs += p;
          }
        rs += __shfl_xor(rs, 16);
        rs += __shfl_xor(rs, 32);
        l_r[mf] += rs;
#pragma unroll
        for (int ks2 = 0; ks2 < 2; ks2++) {
          bf16x8 t2;
#pragma unroll
          for (int r = 0; r < 4; r++) {
            t2[r] = (__bf16)sv[mf][2 * ks2][r];
            t2[4 + r] = (__bf16)sv[mf][2 * ks2 + 1][r];
          }
          pf[mf][ks2] = t2;
        }
      }

      __builtin_amdgcn_s_setprio(1);
#pragma unroll
      for (int ks2 = 0; ks2 < 2; ks2++)
#pragma unroll
        for (int f = 0; f < 8; f++) {
          bf16x8 vf = *(const bf16x8*)&Vl[cur][vidx(f * 16 + lr, ks2 * 64 + lg * 16)];
          acc[0][f] = __builtin_amdgcn_mfma_f32_16x16x32_bf16(pf[0][ks2], vf, acc[0][f], 0, 0, 0);
          acc[1][f] = __builtin_amdgcn_mfma_f32_16x16x32_bf16(pf[1][ks2], vf, acc[1][f], 0, 0, 0);
        }
      __builtin_amdgcn_s_setprio(0);
    }
    __syncthreads();
    cur ^= 1;
  }

#pragma unroll
  for (int mf = 0; mf < 2; mf++) {
    float invl = 1.0f / l_r[mf];
#pragma unroll
    for (int r = 0; r < 4; r++) {
      float ia = __shfl(invl, (lane & 0x30) | (lg * 4 + r));
      int rowg = b * S_LEN + q0w + mf * 16 + lg * 4 + r;
#pragma unroll
      for (int f = 0; f < 8; f++) {
        int colg = h * DKH + f * 16 + lr;
        ctx[(size_t)rowg * DM + colg] = f2bf(acc[mf][f][r] * ia);
      }
    }
  }
}

extern "C" void kernel_launch(void* const* d_in, const int* in_sizes, int n_in,
                              void* d_out, int out_size, void* d_ws, size_t ws_size,
                              hipStream_t stream) {
  const float* x = (const float*)d_in[0];
  const float* Wq = (const float*)d_in[1];
  const float* Wk = (const float*)d_in[2];
  const float* Wv = (const float*)d_in[3];
  const float* Wo = (const float*)d_in[4];
  float* out = (float*)d_out;

  char* ws = (char*)d_ws;
  size_t off = 0;
  auto alloc = [&](size_t bytes) -> char* {
    char* p = ws + off;
    off += (bytes + 255) & ~(size_t)255;
    return p;
  };
  u16* xb = (u16*)alloc((size_t)NROWS * DM * 2);        // reused as ctx
  u16* wqkv = (u16*)alloc((size_t)3 * DM * DM * 2);     // [Wq;Wk;Wv] rows
  u16* wob = (u16*)alloc((size_t)DM * DM * 2);
  u16* Qb = (u16*)alloc((size_t)NROWS * DM * 2);
  u16* Kb = (u16*)alloc((size_t)NROWS * DM * 2);
  u16* Vtb = (u16*)alloc((size_t)NROWS * DM * 2);
  float* cost = (float*)alloc((size_t)S_LEN * 64 * 4);
  float* sint = (float*)alloc((size_t)S_LEN * 64 * 4);
  u16* ctx = xb;

  // allow 128KB dynamic LDS (host-side attribute; not a stream op -> capture-safe)
  hipFuncSetAttribute((const void*)gemm256_kernel<2>,
                      hipFuncAttributeMaxDynamicSharedMemorySize, 131072);
  hipFuncSetAttribute((const void*)gemm256_kernel<0>,
                      hipFuncAttributeMaxDynamicSharedMemorySize, 131072);

  {
    int n4 = NROWS * DM / 4;
    cast_kernel<<<(n4 + 255) / 256, 256, 0, stream>>>(x, xb, n4);
    int w4 = DM * DM / 4;
    cast_kernel<<<(w4 + 255) / 256, 256, 0, stream>>>(Wq, wqkv, w4);
    cast_kernel<<<(w4 + 255) / 256, 256, 0, stream>>>(Wk, wqkv + (size_t)DM * DM, w4);
    cast_kernel<<<(w4 + 255) / 256, 256, 0, stream>>>(Wv, wqkv + (size_t)2 * DM * DM, w4);
    cast_kernel<<<(w4 + 255) / 256, 256, 0, stream>>>(Wo, wob, w4);
  }
  rope_table_kernel<<<(S_LEN * 64 + 255) / 256, 256, 0, stream>>>(cost, sint);

  // fused QKV projection: A=xb [4096x2048], B=wqkv [6144x2048]
  gemm256_kernel<2><<<dim3(3 * DM / 256, NROWS / 256), 512, 131072, stream>>>(
      xb, wqkv, Qb, Kb, Vtb, NROWS, 3 * DM, DM);

  {
    int np = NROWS * 1024;
    rope_apply_kernel<<<(np + 255) / 256, 256, 0, stream>>>(Qb, cost, sint);
    rope_apply_kernel<<<(np + 255) / 256, 256, 0, stream>>>(Kb, cost, sint);
  }

  attn_kernel<<<dim3(NB * NH, S_LEN / 128), 256, 0, stream>>>(Qb, Kb, Vtb, ctx);

  // output projection: A=ctx [4096x2048], B=wob [2048x2048] -> f32 out
  gemm256_kernel<0><<<dim3(DM / 256, NROWS / 256), 512, 131072, stream>>>(
      ctx, wob, out, nullptr, nullptr, NROWS, DM, DM);
}

// Round 5
// 284.263 us; speedup vs baseline: 1.8374x; 1.0494x over previous
//
#include <hip/hip_runtime.h>
#include <stdint.h>
#include <type_traits>

#define S_LEN 2048
#define DM 2048
#define NH 16
#define DKH 128
#define NB 2
#define NROWS (NB * S_LEN)  // 4096

typedef unsigned short u16;
typedef __attribute__((ext_vector_type(8))) __bf16 bf16x8;
typedef __attribute__((ext_vector_type(4))) float f32x4;

__device__ __forceinline__ float bf2f(u16 u) {
  union { unsigned u; float f; } v; v.u = ((unsigned)u) << 16; return v.f;
}
__device__ __forceinline__ u16 f2bf(float f) {
  union { float f; unsigned u; } v; v.f = f;
  unsigned r = v.u + 0x7FFFu + ((v.u >> 16) & 1u);
  return (u16)(r >> 16);
}

// async global->LDS, 16B per lane. lds = WAVE-UNIFORM chunk base (HW adds lane*16);
// g = PER-LANE global address.
__device__ __forceinline__ void async_copy16(void* lds, const void* g) {
  __builtin_amdgcn_global_load_lds(
      (const __attribute__((address_space(1))) unsigned int*)g,
      (__attribute__((address_space(3))) unsigned int*)lds, 16, 0, 0);
}

// ---------------- fused cast fp32 -> bf16 for all 5 inputs ----------------
__global__ void cast_all_kernel(const float* __restrict__ x, const float* __restrict__ wq,
                                const float* __restrict__ wk, const float* __restrict__ wv,
                                const float* __restrict__ wo, u16* __restrict__ xb,
                                u16* __restrict__ wqkv, u16* __restrict__ wob) {
  const int XN4 = NROWS * DM / 4;  // 2^21
  const int WN4 = DM * DM / 4;     // 2^20
  int total = XN4 + 4 * WN4;
  int stride = gridDim.x * blockDim.x;
  for (int i = blockIdx.x * blockDim.x + threadIdx.x; i < total; i += stride) {
    const float* s;
    u16* d;
    int j;
    if (i < XN4) {
      s = x; d = xb; j = i;
    } else {
      int k = i - XN4;
      int w = k >> 20;
      j = k & 0xFFFFF;
      if (w == 0) { s = wq; d = wqkv; }
      else if (w == 1) { s = wk; d = wqkv + (size_t)DM * DM; }
      else if (w == 2) { s = wv; d = wqkv + (size_t)2 * DM * DM; }
      else { s = wo; d = wob; }
    }
    float4 v = ((const float4*)s)[j];
    unsigned r0 = (unsigned)f2bf(v.x) | ((unsigned)f2bf(v.y) << 16);
    unsigned r1 = (unsigned)f2bf(v.z) | ((unsigned)f2bf(v.w) << 16);
    ((uint2*)d)[j] = make_uint2(r0, r1);
  }
}

// ---------------- RoPE cos/sin table: float2[S][64] ----------------
__global__ void rope_table_kernel(float2* __restrict__ ctab) {
  int idx = blockIdx.x * blockDim.x + threadIdx.x;
  if (idx >= S_LEN * 64) return;
  int s = idx >> 6, i = idx & 63;
  float inv = expf(-9.210340371976184f * (float)i * (1.0f / 64.0f));
  float fr = (float)s * inv;
  ctab[idx] = make_float2(cosf(fr), sinf(fr));
}

// ================= 256x256 8-phase GEMM (m201 template, exact) =================
// C = A(MxK) * B(NxK)^T. BK=64, 8 waves (2M x 4N), per-wave 128x64 output.
// LDS 128KB: [A-even][B-even][A-odd][B-odd], each 32K = two 16K halves (128 rows
// x 64 cols bf16), XOR-swizzled (byte ^= (row&7)<<4) via pre-swizzled source.
// Phase = {ds_read frags, stage half-tile, [waits], BAR_a, lgkmcnt(0)+sched_barrier,
//          setprio(1) 16xMFMA setprio(0), BAR_b}. vmcnt(4) only at ph3/ph7.
// Stage slots (iter i computes tiles 2i even-buf, 2i+1 odd-buf):
//   ph0/1: A-odd <- 2i+1;  ph2/3: B-even <- 2i+2;  ph4/5: A-even <- 2i+2;
//   ph6/7: B-odd <- 2i+3.
// Ledger: ph3 vmcnt(4) drains BO(2i+1)+AO(2i+1) [needed ph4-7], leaves BE(2i+2).
//         ph7 vmcnt(4) drains BE+AE(2i+2) [needed next ph0-3], leaves BO(2i+3).
// EPI 0: f32 row-major out (C0). EPI 2: QKV split, RoPE fused on Q/K cols,
//        V cols stored transposed into Vt[(b*16+h)*128+d][s].
#define LDS_AE 0
#define LDS_BE 32768
#define LDS_AO 65536
#define LDS_BO 98304

template <int EPI>
__global__ __launch_bounds__(512, 1) void gemm256_kernel(const u16* __restrict__ A,
                                                         const u16* __restrict__ B,
                                                         void* __restrict__ C0,
                                                         void* __restrict__ C1,
                                                         void* __restrict__ C2,
                                                         const float2* __restrict__ ctab,
                                                         int M, int N, int Kd) {
  extern __shared__ char smem[];
  u16* lds = (u16*)smem;

  int tid = threadIdx.x;
  int lane = tid & 63, wave = tid >> 6;
  int lr = lane & 15, lg = lane >> 4;
  int wm = wave >> 2, wn = wave & 3;

  // bijective XCD swizzle (nwg % 8 == 0 for all launches here)
  int gx = gridDim.x, nwg = gx * gridDim.y;
  int bid = blockIdx.y * gx + blockIdx.x;
  int cpx = nwg >> 3;
  int swz = (bid & 7) * cpx + (bid >> 3);
  int tm = (swz / gx) * 256, tn = (swz % gx) * 256;

  // staging: chunk ch = l*8+wave covers LDS [base+ch*1024,+1024) = rows [ch*8,+8)
  int srow_in = lane >> 3;                             // 0..7
  int scolb = ((lane & 7) * 16) ^ ((lane >> 3) << 4);  // pre-swizzled src byte-col

  const u16* Arows = A + (size_t)tm * Kd;
  const u16* Brows = B + (size_t)tn * Kd;

  auto stage = [&](int halfBase, const u16* Grows, int rowOff, int kt) {
#pragma unroll
    for (int l = 0; l < 2; l++) {
      int ch = l * 8 + wave;
      async_copy16(lds + ((halfBase + ch * 1024) >> 1),
                   Grows + (size_t)(rowOff + ch * 8 + srow_in) * Kd + kt * 64 + (scolb >> 1));
    }
  };

  int arow_b = lr * 128;
  int acolb[2];
#pragma unroll
  for (int ks = 0; ks < 2; ks++) acolb[ks] = (ks * 64 + lg * 16) ^ ((lr & 7) << 4);
  int aBaseW = wm * 16384;
  int bhrow_b = (wn >> 1) * 16384 + ((wn & 1) * 64 + lr) * 128;

  f32x4 zero4 = {0.f, 0.f, 0.f, 0.f};
  f32x4 acc[8][4];
#pragma unroll
  for (int i = 0; i < 8; i++)
#pragma unroll
    for (int j = 0; j < 4; j++) acc[i][j] = zero4;

  bf16x8 bpre[4][2];
  bf16x8 af[2][2];

  auto loadB = [&](int bBase) {
#pragma unroll
    for (int nf = 0; nf < 4; nf++)
#pragma unroll
      for (int ks = 0; ks < 2; ks++)
        bpre[nf][ks] = *(const bf16x8*)&lds[(bBase + bhrow_b + nf * 2048 + acolb[ks]) >> 1];
  };
  auto readA = [&](int aBase, int q) {
#pragma unroll
    for (int dm = 0; dm < 2; dm++)
#pragma unroll
      for (int ks = 0; ks < 2; ks++)
        af[dm][ks] =
            *(const bf16x8*)&lds[(aBase + aBaseW + (2 * q + dm) * 2048 + arow_b + acolb[ks]) >> 1];
  };
  auto mfma16 = [&](auto qc) {
    constexpr int Q = decltype(qc)::value;
    __builtin_amdgcn_s_setprio(1);
#pragma unroll
    for (int dm = 0; dm < 2; dm++)
#pragma unroll
      for (int nf = 0; nf < 4; nf++)
#pragma unroll
        for (int ks = 0; ks < 2; ks++)
          acc[2 * Q + dm][nf] = __builtin_amdgcn_mfma_f32_16x16x32_bf16(
              af[dm][ks], bpre[nf][ks], acc[2 * Q + dm][nf], 0, 0, 0);
    __builtin_amdgcn_s_setprio(0);
  };
  auto bar_pre = [&]() {
    __builtin_amdgcn_s_barrier();
    asm volatile("s_waitcnt lgkmcnt(0)" ::: "memory");
    __builtin_amdgcn_sched_barrier(0);
  };

  int nk = Kd >> 6;
  int nIter = nk >> 1;

  // ---- prologue: AE(t0), BE(t0), BO(t1); confirm AE+BE (leave BO in flight) ----
  stage(LDS_AE + 0, Arows, 0, 0);
  stage(LDS_AE + 16384, Arows, 128, 0);
  stage(LDS_BE + 0, Brows, 0, 0);
  stage(LDS_BE + 16384, Brows, 128, 0);
  stage(LDS_BO + 0, Brows, 0, 1);
  stage(LDS_BO + 16384, Brows, 128, 1);
  asm volatile("s_waitcnt vmcnt(4)" ::: "memory");
  __builtin_amdgcn_s_barrier();

  for (int i = 0; i < nIter; i++) {
    int tO = 2 * i + 1;
    int tE2 = 2 * i + 2; if (tE2 > nk - 1) tE2 = nk - 1;
    int tO2 = 2 * i + 3; if (tO2 > nk - 1) tO2 = nk - 1;

    // ---- ph0 ----
    loadB(LDS_BE); readA(LDS_AE, 0);
    stage(LDS_AO + 0, Arows, 0, tO);
    asm volatile("s_waitcnt lgkmcnt(8)" ::: "memory");
    bar_pre();
    mfma16(std::integral_constant<int, 0>{});
    __builtin_amdgcn_s_barrier();
    // ---- ph1 ----
    readA(LDS_AE, 1);
    stage(LDS_AO + 16384, Arows, 128, tO);
    bar_pre();
    mfma16(std::integral_constant<int, 1>{});
    __builtin_amdgcn_s_barrier();
    // ---- ph2 ----
    readA(LDS_AE, 2);
    stage(LDS_BE + 0, Brows, 0, tE2);
    bar_pre();
    mfma16(std::integral_constant<int, 2>{});
    __builtin_amdgcn_s_barrier();
    // ---- ph3 ----
    readA(LDS_AE, 3);
    stage(LDS_BE + 16384, Brows, 128, tE2);
    asm volatile("s_waitcnt vmcnt(4)" ::: "memory");
    bar_pre();
    mfma16(std::integral_constant<int, 3>{});
    __builtin_amdgcn_s_barrier();
    // ---- ph4 ----
    loadB(LDS_BO); readA(LDS_AO, 0);
    stage(LDS_AE + 0, Arows, 0, tE2);
    asm volatile("s_waitcnt lgkmcnt(8)" ::: "memory");
    bar_pre();
    mfma16(std::integral_constant<int, 0>{});
    __builtin_amdgcn_s_barrier();
    // ---- ph5 ----
    readA(LDS_AO, 1);
    stage(LDS_AE + 16384, Arows, 128, tE2);
    bar_pre();
    mfma16(std::integral_constant<int, 1>{});
    __builtin_amdgcn_s_barrier();
    // ---- ph6 ----
    readA(LDS_AO, 2);
    stage(LDS_BO + 0, Brows, 0, tO2);
    bar_pre();
    mfma16(std::integral_constant<int, 2>{});
    __builtin_amdgcn_s_barrier();
    // ---- ph7 ----
    readA(LDS_AO, 3);
    stage(LDS_BO + 16384, Brows, 128, tO2);
    asm volatile("s_waitcnt vmcnt(4)" ::: "memory");
    bar_pre();
    mfma16(std::integral_constant<int, 3>{});
    __builtin_amdgcn_s_barrier();
  }

  asm volatile("s_waitcnt vmcnt(0)" ::: "memory");  // drain dangling prefetches

  // ---- epilogue: row = tm + wm*128 + mf*16 + lg*4 (+r); col = tn + wn*64 + nf*16 + lr ----
#pragma unroll
  for (int mf = 0; mf < 8; mf++) {
    int row = tm + wm * 128 + mf * 16 + lg * 4;
#pragma unroll
    for (int nf = 0; nf < 4; nf++) {
      int col = tn + wn * 64 + nf * 16 + lr;
      if constexpr (EPI == 0) {
        float* O = (float*)C0;
#pragma unroll
        for (int r = 0; r < 4; r++) O[(size_t)(row + r) * N + col] = acc[mf][nf][r];
      } else {
        int mat = col >> 11, lc = col & 2047;  // wave-uniform mat (256-col blocks)
        if (mat < 2) {
          // fused RoPE (fp32): pair (2i,2i+1) along d lives in lanes lr, lr^1
          u16* O = (mat == 0) ? (u16*)C0 : (u16*)C1;
          int d = lc & 127;
          bool odd = (d & 1) != 0;
          const float2* ct = ctab + (d >> 1);
#pragma unroll
          for (int r = 0; r < 4; r++) {
            float a = acc[mf][nf][r];
            float p = __shfl_xor(a, 1);
            int sIdx = (row + r) & (S_LEN - 1);
            float2 cs = ct[sIdx * 64];
            float o = odd ? (p * cs.y + a * cs.x) : (a * cs.x - p * cs.y);
            O[(size_t)(row + r) * 2048 + lc] = f2bf(o);
          }
        } else {
          u16* O = (u16*)C2;  // Vt[(b*16+h)*128 + d][s]
          int h = lc >> 7, d = lc & 127;
          int bb = row >> 11, s0 = row & 2047;
          unsigned w0 = (unsigned)f2bf(acc[mf][nf][0]) | ((unsigned)f2bf(acc[mf][nf][1]) << 16);
          unsigned w1 = (unsigned)f2bf(acc[mf][nf][2]) | ((unsigned)f2bf(acc[mf][nf][3]) << 16);
          *(uint2*)(O + ((size_t)((bb * 16 + h) * 128 + d) * 2048 + s0)) = make_uint2(w0, w1);
        }
      }
    }
  }
}

// ---------------- causal flash attention (swapped-QK, P in registers) ----------------
__device__ __forceinline__ int kidx(int row, int colb) {  // Kl [64][128] u16
  return ((row << 8) + (colb ^ ((row & 7) << 4))) >> 1;
}
__device__ __forceinline__ int vidx(int row, int colb) {  // Vl [128][64] u16
  return ((row << 7) + (colb ^ ((row & 7) << 4))) >> 1;
}

__global__ __launch_bounds__(256, 2) void attn_kernel(const u16* __restrict__ Q,
                                                      const u16* __restrict__ K,
                                                      const u16* __restrict__ Vt,
                                                      u16* __restrict__ ctx) {
  __shared__ u16 Kl[2][64 * 128];
  __shared__ u16 Vl[2][128 * 64];

  int tid = threadIdx.x;
  int lane = tid & 63, wave = tid >> 6;
  int lr = lane & 15, lg = lane >> 4;
  int bh = blockIdx.x;
  int b = bh >> 4, h = bh & 15;
  int qt = (gridDim.y - 1) - blockIdx.y;
  int q0 = qt * 128;
  int q0w = q0 + wave * 32;

  bf16x8 qf[2][4];
#pragma unroll
  for (int mf = 0; mf < 2; mf++) {
    const u16* qbase = Q + (size_t)(b * S_LEN + q0w + mf * 16 + lr) * DM + h * DKH;
#pragma unroll
    for (int ks = 0; ks < 4; ks++) qf[mf][ks] = *(const bf16x8*)(qbase + ks * 32 + lg * 8);
  }

  f32x4 zero4 = {0.f, 0.f, 0.f, 0.f};
  f32x4 acc[2][8];
#pragma unroll
  for (int mf = 0; mf < 2; mf++)
#pragma unroll
    for (int f = 0; f < 8; f++) acc[mf][f] = zero4;
  float m_r[2], l_r[2];
#pragma unroll
  for (int mf = 0; mf < 2; mf++) { m_r[mf] = -3.0e38f; l_r[mf] = 0.f; }

  const float SL2E = 1.4426950408889634f * 0.08838834764831845f;
  const float RTHR = 64.0f;

  const u16* Kbh = K + (size_t)b * S_LEN * DM + h * DKH;
  const u16* Vbh = Vt + (size_t)(b * NH + h) * DKH * S_LEN;

  auto stage = [&](int buf, int kv0s) {
#pragma unroll
    for (int c = 0; c < 4; c++) {
      int ch = wave * 4 + c;
      int krow = ch * 4 + (lane >> 4);
      int kphi = (krow & 0x23) | ((krow & 0x10) >> 2) | ((krow & 0x0C) << 1);
      int kcb = ((((lane & 15) << 4) ^ ((krow & 7) << 4)) >> 1);
      async_copy16(&Kl[buf][ch * 512], Kbh + (size_t)(kv0s + kphi) * DM + kcb);
      int vrow = ch * 8 + (lane >> 3);
      int vcb = ((((lane & 7) << 4) ^ ((vrow & 7) << 4)) >> 1);
      async_copy16(&Vl[buf][ch * 512], Vbh + (size_t)vrow * S_LEN + kv0s + vcb);
    }
  };

  int ntiles = 2 * qt + 2;
  stage(0, 0);
  __syncthreads();
  int cur = 0;

  for (int t = 0; t < ntiles; t++) {
    int kv0 = t * 64;
    if (t + 1 < ntiles) stage(cur ^ 1, (t + 1) * 64);

    if (kv0 <= q0w + 31) {
      bool need_mask = (kv0 + 63 > q0w);

      f32x4 sf[4][2];
#pragma unroll
      for (int kf = 0; kf < 4; kf++)
#pragma unroll
        for (int mf = 0; mf < 2; mf++) sf[kf][mf] = zero4;
      __builtin_amdgcn_s_setprio(1);
#pragma unroll
      for (int ks = 0; ks < 4; ks++)
#pragma unroll
        for (int kf = 0; kf < 4; kf++) {
          bf16x8 kfrag = *(const bf16x8*)&Kl[cur][kidx(kf * 16 + lr, ks * 64 + lg * 16)];
          sf[kf][0] = __builtin_amdgcn_mfma_f32_16x16x32_bf16(kfrag, qf[0][ks], sf[kf][0], 0, 0, 0);
          sf[kf][1] = __builtin_amdgcn_mfma_f32_16x16x32_bf16(kfrag, qf[1][ks], sf[kf][1], 0, 0, 0);
        }
      __builtin_amdgcn_s_setprio(0);

      float sv[2][4][4];
      float mx[2];
#pragma unroll
      for (int mf = 0; mf < 2; mf++) {
        int qg = q0w + mf * 16 + lr;
        mx[mf] = -3.0e38f;
#pragma unroll
        for (int kf = 0; kf < 4; kf++) {
          int kvb = kv0 + (kf >> 1) * 32 + (kf & 1) * 4 + lg * 8;
#pragma unroll
          for (int r = 0; r < 4; r++) {
            float x = sf[kf][mf][r];
            if (need_mask) x = (kvb + r <= qg) ? x : -3.0e38f;
            sv[mf][kf][r] = x;
            mx[mf] = fmaxf(mx[mf], x);
          }
        }
        mx[mf] = fmaxf(mx[mf], __shfl_xor(mx[mf], 16));
        mx[mf] = fmaxf(mx[mf], __shfl_xor(mx[mf], 32));
      }

      bool need = (mx[0] > m_r[0] + RTHR) | (mx[1] > m_r[1] + RTHR);
      if (__any(need)) {
        float scs[2];
#pragma unroll
        for (int mf = 0; mf < 2; mf++) {
          float mnew = fmaxf(m_r[mf], mx[mf]);
          scs[mf] = __builtin_amdgcn_exp2f((m_r[mf] - mnew) * SL2E);
          m_r[mf] = mnew;
          l_r[mf] *= scs[mf];
        }
#pragma unroll
        for (int mf = 0; mf < 2; mf++) {
#pragma unroll
          for (int r = 0; r < 4; r++) {
            float sa = __shfl(scs[mf], (lane & 0x30) | (lg * 4 + r));
#pragma unroll
            for (int f = 0; f < 8; f++) acc[mf][f][r] *= sa;
          }
        }
      }

      bf16x8 pf[2][2];
#pragma unroll
      for (int mf = 0; mf < 2; mf++) {
        float rs = 0.f;
#pragma unroll
        for (int kf = 0; kf < 4; kf++)
#pragma unroll
          for (int r = 0; r < 4; r++) {
            float p = __builtin_amdgcn_exp2f((sv[mf][kf][r] - m_r[mf]) * SL2E);
            sv[mf][kf][r] = p;
            rs += p;
          }
        rs += __shfl_xor(rs, 16);
        rs += __shfl_xor(rs, 32);
        l_r[mf] += rs;
#pragma unroll
        for (int ks2 = 0; ks2 < 2; ks2++) {
          bf16x8 t2;
#pragma unroll
          for (int r = 0; r < 4; r++) {
            t2[r] = (__bf16)sv[mf][2 * ks2][r];
            t2[4 + r] = (__bf16)sv[mf][2 * ks2 + 1][r];
          }
          pf[mf][ks2] = t2;
        }
      }

      __builtin_amdgcn_s_setprio(1);
#pragma unroll
      for (int ks2 = 0; ks2 < 2; ks2++)
#pragma unroll
        for (int f = 0; f < 8; f++) {
          bf16x8 vf = *(const bf16x8*)&Vl[cur][vidx(f * 16 + lr, ks2 * 64 + lg * 16)];
          acc[0][f] = __builtin_amdgcn_mfma_f32_16x16x32_bf16(pf[0][ks2], vf, acc[0][f], 0, 0, 0);
          acc[1][f] = __builtin_amdgcn_mfma_f32_16x16x32_bf16(pf[1][ks2], vf, acc[1][f], 0, 0, 0);
        }
      __builtin_amdgcn_s_setprio(0);
    }
    __syncthreads();
    cur ^= 1;
  }

#pragma unroll
  for (int mf = 0; mf < 2; mf++) {
    float invl = 1.0f / l_r[mf];
#pragma unroll
    for (int r = 0; r < 4; r++) {
      float ia = __shfl(invl, (lane & 0x30) | (lg * 4 + r));
      int rowg = b * S_LEN + q0w + mf * 16 + lg * 4 + r;
#pragma unroll
      for (int f = 0; f < 8; f++) {
        int colg = h * DKH + f * 16 + lr;
        ctx[(size_t)rowg * DM + colg] = f2bf(acc[mf][f][r] * ia);
      }
    }
  }
}

extern "C" void kernel_launch(void* const* d_in, const int* in_sizes, int n_in,
                              void* d_out, int out_size, void* d_ws, size_t ws_size,
                              hipStream_t stream) {
  const float* x = (const float*)d_in[0];
  const float* Wq = (const float*)d_in[1];
  const float* Wk = (const float*)d_in[2];
  const float* Wv = (const float*)d_in[3];
  const float* Wo = (const float*)d_in[4];
  float* out = (float*)d_out;

  char* ws = (char*)d_ws;
  size_t off = 0;
  auto alloc = [&](size_t bytes) -> char* {
    char* p = ws + off;
    off += (bytes + 255) & ~(size_t)255;
    return p;
  };
  u16* xb = (u16*)alloc((size_t)NROWS * DM * 2);     // reused as ctx
  u16* wqkv = (u16*)alloc((size_t)3 * DM * DM * 2);  // [Wq;Wk;Wv] rows
  u16* wob = (u16*)alloc((size_t)DM * DM * 2);
  u16* Qb = (u16*)alloc((size_t)NROWS * DM * 2);
  u16* Kb = (u16*)alloc((size_t)NROWS * DM * 2);
  u16* Vtb = (u16*)alloc((size_t)NROWS * DM * 2);
  float2* ctab = (float2*)alloc((size_t)S_LEN * 64 * 8);
  u16* ctx = xb;

  // allow 128KB dynamic LDS (host-side attribute; capture-safe)
  hipFuncSetAttribute((const void*)gemm256_kernel<2>,
                      hipFuncAttributeMaxDynamicSharedMemorySize, 131072);
  hipFuncSetAttribute((const void*)gemm256_kernel<0>,
                      hipFuncAttributeMaxDynamicSharedMemorySize, 131072);

  cast_all_kernel<<<2048, 256, 0, stream>>>(x, Wq, Wk, Wv, Wo, xb, wqkv, wob);
  rope_table_kernel<<<(S_LEN * 64 + 255) / 256, 256, 0, stream>>>(ctab);

  // fused QKV projection + RoPE + V-transpose: A=xb [4096x2048], B=wqkv [6144x2048]
  gemm256_kernel<2><<<dim3(3 * DM / 256, NROWS / 256), 512, 131072, stream>>>(
      xb, wqkv, Qb, Kb, Vtb, ctab, NROWS, 3 * DM, DM);

  attn_kernel<<<dim3(NB * NH, S_LEN / 128), 256, 0, stream>>>(Qb, Kb, Vtb, ctx);

  // output projection: A=ctx [4096x2048], B=wob [2048x2048] -> f32 out
  gemm256_kernel<0><<<dim3(DM / 256, NROWS / 256), 512, 131072, stream>>>(
      ctx, wob, out, nullptr, nullptr, nullptr, NROWS, DM, DM);
}

// Round 6
// 251.821 us; speedup vs baseline: 2.0741x; 1.1288x over previous
//
#include <hip/hip_runtime.h>
#include <stdint.h>
#include <type_traits>

#define S_LEN 2048
#define DM 2048
#define NH 16
#define DKH 128
#define NB 2
#define NROWS (NB * S_LEN)  // 4096

typedef unsigned short u16;
typedef __attribute__((ext_vector_type(8))) __bf16 bf16x8;
typedef __attribute__((ext_vector_type(4))) float f32x4;

__device__ __forceinline__ float bf2f(u16 u) {
  union { unsigned u; float f; } v; v.u = ((unsigned)u) << 16; return v.f;
}
__device__ __forceinline__ u16 f2bf(float f) {
  union { float f; unsigned u; } v; v.f = f;
  unsigned r = v.u + 0x7FFFu + ((v.u >> 16) & 1u);
  return (u16)(r >> 16);
}

// async global->LDS, 16B per lane. lds = WAVE-UNIFORM chunk base (HW adds lane*16);
// g = PER-LANE global address.
__device__ __forceinline__ void async_copy16(void* lds, const void* g) {
  __builtin_amdgcn_global_load_lds(
      (const __attribute__((address_space(1))) unsigned int*)g,
      (__attribute__((address_space(3))) unsigned int*)lds, 16, 0, 0);
}

// ---------------- fused cast fp32 -> bf16 for all 5 inputs ----------------
__global__ void cast_all_kernel(const float* __restrict__ x, const float* __restrict__ wq,
                                const float* __restrict__ wk, const float* __restrict__ wv,
                                const float* __restrict__ wo, u16* __restrict__ xb,
                                u16* __restrict__ wqkv, u16* __restrict__ wob) {
  const int XN4 = NROWS * DM / 4;  // 2^21
  const int WN4 = DM * DM / 4;     // 2^20
  int total = XN4 + 4 * WN4;
  int stride = gridDim.x * blockDim.x;
  for (int i = blockIdx.x * blockDim.x + threadIdx.x; i < total; i += stride) {
    const float* s;
    u16* d;
    int j;
    if (i < XN4) {
      s = x; d = xb; j = i;
    } else {
      int k = i - XN4;
      int w = k >> 20;
      j = k & 0xFFFFF;
      if (w == 0) { s = wq; d = wqkv; }
      else if (w == 1) { s = wk; d = wqkv + (size_t)DM * DM; }
      else if (w == 2) { s = wv; d = wqkv + (size_t)2 * DM * DM; }
      else { s = wo; d = wob; }
    }
    float4 v = ((const float4*)s)[j];
    unsigned r0 = (unsigned)f2bf(v.x) | ((unsigned)f2bf(v.y) << 16);
    unsigned r1 = (unsigned)f2bf(v.z) | ((unsigned)f2bf(v.w) << 16);
    ((uint2*)d)[j] = make_uint2(r0, r1);
  }
}

// ---------------- RoPE cos/sin table: float2[S][64] ----------------
__global__ void rope_table_kernel(float2* __restrict__ ctab) {
  int idx = blockIdx.x * blockDim.x + threadIdx.x;
  if (idx >= S_LEN * 64) return;
  int s = idx >> 6, i = idx & 63;
  float inv = expf(-9.210340371976184f * (float)i * (1.0f / 64.0f));
  float fr = (float)s * inv;
  ctab[idx] = make_float2(cosf(fr), sinf(fr));
}

// ================= 256 x (64*NSEG) 8-phase GEMM (m201 template) =================
// C = A(MxK) * B(NxK)^T. BM=256, BN=64*NSEG (NSEG=3: 192, NSEG=2: 128), BK=64,
// 8 waves (2M x 4N), per-wave 128 x (16*NSEG) output.
// LDS: A dbuf 2x32KB + B dbuf 2x(BN*128)B, flat [rows][64] bf16, XOR-swizzled
// (byte ^= (row&7)<<4) via pre-swizzled global_load_lds source.
// A staged in 2 halves of 128 rows (2 loads/thread); B in NSEG segs of 64 rows
// (1 load/thread) -> per-wave-uniform vmcnt ledger.
// Stage slots (iter i computes tiles 2i even, 2i+1 odd):
//   ph0/1: A-odd halves <- 2i+1; ph2/3: B-even segs <- 2i+2;
//   ph4/5: A-even halves <- 2i+2; ph6/7: B-odd segs <- 2i+3.
// vmcnt(NSEG) only at ph3/ph7 (drains prev B + new A, leaves next-B in flight).
// EPI 0: f32 row-major out (C0). EPI 2: QKV split by col (per-frag): [0,2048)->
// Q(C0)+RoPE, [2048,4096)->K(C1)+RoPE, [4096,6144)->Vt(C2) transposed.
template <int NSEG, int EPI>
__global__ __launch_bounds__(512, 1) void gemm256_kernel(const u16* __restrict__ A,
                                                         const u16* __restrict__ B,
                                                         void* __restrict__ C0,
                                                         void* __restrict__ C1,
                                                         void* __restrict__ C2,
                                                         const float2* __restrict__ ctab,
                                                         int M, int N, int Kd) {
  constexpr int BN = 64 * NSEG;
  constexpr int BSZ = BN * 128;  // bytes per B buffer
  constexpr int LDS_AE = 0, LDS_AO = 32768, LDS_BE = 65536, LDS_BO = 65536 + BSZ;

  extern __shared__ char smem[];
  u16* lds = (u16*)smem;

  int tid = threadIdx.x;
  int lane = tid & 63, wave = tid >> 6;
  int lr = lane & 15, lg = lane >> 4;
  int wm = wave >> 2, wn = wave & 3;

  // bijective XCD swizzle (nwg % 8 == 0 for all launches here)
  int gx = gridDim.x, nwg = gx * gridDim.y;
  int bid = blockIdx.y * gx + blockIdx.x;
  int cpx = nwg >> 3;
  int swz = (bid & 7) * cpx + (bid >> 3);
  int tm = (swz / gx) * 256, tn = (swz % gx) * BN;

  // staging geometry: chunk = 1KB = 8 rows; dest linear, source pre-swizzled
  int srow_in = lane >> 3;                             // 0..7
  int scolb = ((lane & 7) * 16) ^ ((lane >> 3) << 4);  // pre-swizzled src byte-col

  const u16* Arows = A + (size_t)tm * Kd;
  const u16* Brows = B + (size_t)tn * Kd;

  auto stageA = [&](int aBase, int h, int kt) {  // half h = 128 rows, 2 loads
#pragma unroll
    for (int l = 0; l < 2; l++) {
      int ch = h * 16 + l * 8 + wave;
      async_copy16(lds + ((aBase + ch * 1024) >> 1),
                   Arows + (size_t)(ch * 8 + srow_in) * Kd + kt * 64 + (scolb >> 1));
    }
  };
  auto stageB = [&](int bBase, int s, int kt) {  // seg s = 64 rows, 1 load
    int ch = s * 8 + wave;
    async_copy16(lds + ((bBase + ch * 1024) >> 1),
                 Brows + (size_t)(ch * 8 + srow_in) * Kd + kt * 64 + (scolb >> 1));
  };

  int acolb[2];
#pragma unroll
  for (int ks = 0; ks < 2; ks++) acolb[ks] = (ks * 64 + lg * 16) ^ ((lr & 7) << 4);
  int aBaseW = wm * 128 * 128;         // byte offset of wave's A half (128 rows)
  int brow_b = (wn * 16 * NSEG + lr) * 128;  // wave's first B row byte offset

  f32x4 zero4 = {0.f, 0.f, 0.f, 0.f};
  f32x4 acc[8][NSEG];
#pragma unroll
  for (int i = 0; i < 8; i++)
#pragma unroll
    for (int j = 0; j < NSEG; j++) acc[i][j] = zero4;

  bf16x8 bpre[NSEG][2];
  bf16x8 af[2][2];

  auto loadB = [&](int bBase) {
#pragma unroll
    for (int nf = 0; nf < NSEG; nf++)
#pragma unroll
      for (int ks = 0; ks < 2; ks++)
        bpre[nf][ks] = *(const bf16x8*)&lds[(bBase + brow_b + nf * 2048 + acolb[ks]) >> 1];
  };
  auto readA = [&](int aBase, int q) {
#pragma unroll
    for (int dm = 0; dm < 2; dm++)
#pragma unroll
      for (int ks = 0; ks < 2; ks++)
        af[dm][ks] = *(const bf16x8*)&lds[(aBase + aBaseW + (2 * q + dm) * 2048 + lr * 128 +
                                           acolb[ks]) >> 1];
  };
  auto mfmaC = [&](auto qc) {
    constexpr int Q = decltype(qc)::value;
    __builtin_amdgcn_s_setprio(1);
#pragma unroll
    for (int dm = 0; dm < 2; dm++)
#pragma unroll
      for (int nf = 0; nf < NSEG; nf++)
#pragma unroll
        for (int ks = 0; ks < 2; ks++)
          acc[2 * Q + dm][nf] = __builtin_amdgcn_mfma_f32_16x16x32_bf16(
              af[dm][ks], bpre[nf][ks], acc[2 * Q + dm][nf], 0, 0, 0);
    __builtin_amdgcn_s_setprio(0);
  };
  auto bar_pre = [&]() {
    __builtin_amdgcn_s_barrier();
    asm volatile("s_waitcnt lgkmcnt(0)" ::: "memory");
    __builtin_amdgcn_sched_barrier(0);
  };
  auto vm_wait = [&]() {
    if constexpr (NSEG == 3) asm volatile("s_waitcnt vmcnt(3)" ::: "memory");
    else asm volatile("s_waitcnt vmcnt(2)" ::: "memory");
  };

  int nk = Kd >> 6;
  int nIter = nk >> 1;

  // ---- prologue: AE(t0) + BE(t0) + BO(t1); confirm AE+BE, leave BO in flight ----
  stageA(LDS_AE, 0, 0);
  stageA(LDS_AE, 1, 0);
#pragma unroll
  for (int s = 0; s < NSEG; s++) stageB(LDS_BE, s, 0);
#pragma unroll
  for (int s = 0; s < NSEG; s++) stageB(LDS_BO, s, 1);
  vm_wait();
  __builtin_amdgcn_s_barrier();

  for (int i = 0; i < nIter; i++) {
    int tO = 2 * i + 1;
    int tE2 = 2 * i + 2; if (tE2 > nk - 1) tE2 = nk - 1;
    int tO2 = 2 * i + 3; if (tO2 > nk - 1) tO2 = nk - 1;

    // ---- ph0 ----
    loadB(LDS_BE); readA(LDS_AE, 0);
    stageA(LDS_AO, 0, tO);
    asm volatile("s_waitcnt lgkmcnt(8)" ::: "memory");
    bar_pre();
    mfmaC(std::integral_constant<int, 0>{});
    __builtin_amdgcn_s_barrier();
    // ---- ph1 ----
    readA(LDS_AE, 1);
    stageA(LDS_AO, 1, tO);
    bar_pre();
    mfmaC(std::integral_constant<int, 1>{});
    __builtin_amdgcn_s_barrier();
    // ---- ph2 ----
    readA(LDS_AE, 2);
    stageB(LDS_BE, 0, tE2);
    if constexpr (NSEG == 3) stageB(LDS_BE, 1, tE2);
    bar_pre();
    mfmaC(std::integral_constant<int, 2>{});
    __builtin_amdgcn_s_barrier();
    // ---- ph3 ----
    readA(LDS_AE, 3);
    stageB(LDS_BE, NSEG - 1, tE2);
    vm_wait();
    bar_pre();
    mfmaC(std::integral_constant<int, 3>{});
    __builtin_amdgcn_s_barrier();
    // ---- ph4 ----
    loadB(LDS_BO); readA(LDS_AO, 0);
    stageA(LDS_AE, 0, tE2);
    asm volatile("s_waitcnt lgkmcnt(8)" ::: "memory");
    bar_pre();
    mfmaC(std::integral_constant<int, 0>{});
    __builtin_amdgcn_s_barrier();
    // ---- ph5 ----
    readA(LDS_AO, 1);
    stageA(LDS_AE, 1, tE2);
    bar_pre();
    mfmaC(std::integral_constant<int, 1>{});
    __builtin_amdgcn_s_barrier();
    // ---- ph6 ----
    readA(LDS_AO, 2);
    stageB(LDS_BO, 0, tO2);
    if constexpr (NSEG == 3) stageB(LDS_BO, 1, tO2);
    bar_pre();
    mfmaC(std::integral_constant<int, 2>{});
    __builtin_amdgcn_s_barrier();
    // ---- ph7 ----
    readA(LDS_AO, 3);
    stageB(LDS_BO, NSEG - 1, tO2);
    vm_wait();
    bar_pre();
    mfmaC(std::integral_constant<int, 3>{});
    __builtin_amdgcn_s_barrier();
  }

  asm volatile("s_waitcnt vmcnt(0)" ::: "memory");  // drain dangling prefetches

  // ---- epilogue: row = tm + wm*128 + mf*16 + lg*4 (+r); col = tn + wn*16*NSEG + nf*16 + lr ----
#pragma unroll
  for (int mf = 0; mf < 8; mf++) {
    int row = tm + wm * 128 + mf * 16 + lg * 4;
#pragma unroll
    for (int nf = 0; nf < NSEG; nf++) {
      int col = tn + wn * 16 * NSEG + nf * 16 + lr;
      if constexpr (EPI == 0) {
        float* O = (float*)C0;
#pragma unroll
        for (int r = 0; r < 4; r++) O[(size_t)(row + r) * N + col] = acc[mf][nf][r];
      } else {
        int mat = col >> 11, lc = col & 2047;  // frag-uniform (16-col frags, 2048|16)
        if (mat < 2) {
          // fused RoPE (fp32): pair (2i,2i+1) along d lives in lanes lr, lr^1
          u16* O = (mat == 0) ? (u16*)C0 : (u16*)C1;
          int d = lc & 127;
          bool odd = (d & 1) != 0;
          const float2* ct = ctab + (d >> 1);
#pragma unroll
          for (int r = 0; r < 4; r++) {
            float a = acc[mf][nf][r];
            float p = __shfl_xor(a, 1);
            int sIdx = (row + r) & (S_LEN - 1);
            float2 cs = ct[sIdx * 64];
            float o = odd ? (p * cs.y + a * cs.x) : (a * cs.x - p * cs.y);
            O[(size_t)(row + r) * 2048 + lc] = f2bf(o);
          }
        } else {
          u16* O = (u16*)C2;  // Vt[(b*16+h)*128 + d][s]
          int h = lc >> 7, d = lc & 127;
          int bb = row >> 11, s0 = row & 2047;
          unsigned w0 = (unsigned)f2bf(acc[mf][nf][0]) | ((unsigned)f2bf(acc[mf][nf][1]) << 16);
          unsigned w1 = (unsigned)f2bf(acc[mf][nf][2]) | ((unsigned)f2bf(acc[mf][nf][3]) << 16);
          *(uint2*)(O + ((size_t)((bb * 16 + h) * 128 + d) * 2048 + s0)) = make_uint2(w0, w1);
        }
      }
    }
  }
}

// ---------------- causal flash attention (swapped-QK, P in registers) ----------------
__device__ __forceinline__ int kidx(int row, int colb) {  // Kl [64][128] u16
  return ((row << 8) + (colb ^ ((row & 7) << 4))) >> 1;
}
__device__ __forceinline__ int vidx(int row, int colb) {  // Vl [128][64] u16
  return ((row << 7) + (colb ^ ((row & 7) << 4))) >> 1;
}

__global__ __launch_bounds__(256, 2) void attn_kernel(const u16* __restrict__ Q,
                                                      const u16* __restrict__ K,
                                                      const u16* __restrict__ Vt,
                                                      u16* __restrict__ ctx) {
  __shared__ u16 Kl[2][64 * 128];
  __shared__ u16 Vl[2][128 * 64];

  int tid = threadIdx.x;
  int lane = tid & 63, wave = tid >> 6;
  int lr = lane & 15, lg = lane >> 4;
  int bh = blockIdx.x;
  int b = bh >> 4, h = bh & 15;
  int qt = (gridDim.y - 1) - blockIdx.y;
  int q0 = qt * 128;
  int q0w = q0 + wave * 32;

  bf16x8 qf[2][4];
#pragma unroll
  for (int mf = 0; mf < 2; mf++) {
    const u16* qbase = Q + (size_t)(b * S_LEN + q0w + mf * 16 + lr) * DM + h * DKH;
#pragma unroll
    for (int ks = 0; ks < 4; ks++) qf[mf][ks] = *(const bf16x8*)(qbase + ks * 32 + lg * 8);
  }

  f32x4 zero4 = {0.f, 0.f, 0.f, 0.f};
  f32x4 acc[2][8];
#pragma unroll
  for (int mf = 0; mf < 2; mf++)
#pragma unroll
    for (int f = 0; f < 8; f++) acc[mf][f] = zero4;
  float m_r[2], l_r[2];
#pragma unroll
  for (int mf = 0; mf < 2; mf++) { m_r[mf] = -3.0e38f; l_r[mf] = 0.f; }

  const float SL2E = 1.4426950408889634f * 0.08838834764831845f;
  const float RTHR = 64.0f;

  const u16* Kbh = K + (size_t)b * S_LEN * DM + h * DKH;
  const u16* Vbh = Vt + (size_t)(b * NH + h) * DKH * S_LEN;

  auto stage = [&](int buf, int kv0s) {
#pragma unroll
    for (int c = 0; c < 4; c++) {
      int ch = wave * 4 + c;
      int krow = ch * 4 + (lane >> 4);
      int kphi = (krow & 0x23) | ((krow & 0x10) >> 2) | ((krow & 0x0C) << 1);
      int kcb = ((((lane & 15) << 4) ^ ((krow & 7) << 4)) >> 1);
      async_copy16(&Kl[buf][ch * 512], Kbh + (size_t)(kv0s + kphi) * DM + kcb);
      int vrow = ch * 8 + (lane >> 3);
      int vcb = ((((lane & 7) << 4) ^ ((vrow & 7) << 4)) >> 1);
      async_copy16(&Vl[buf][ch * 512], Vbh + (size_t)vrow * S_LEN + kv0s + vcb);
    }
  };

  int ntiles = 2 * qt + 2;
  stage(0, 0);
  __syncthreads();
  int cur = 0;

  for (int t = 0; t < ntiles; t++) {
    int kv0 = t * 64;
    if (t + 1 < ntiles) stage(cur ^ 1, (t + 1) * 64);

    if (kv0 <= q0w + 31) {
      bool need_mask = (kv0 + 63 > q0w);

      f32x4 sf[4][2];
#pragma unroll
      for (int kf = 0; kf < 4; kf++)
#pragma unroll
        for (int mf = 0; mf < 2; mf++) sf[kf][mf] = zero4;
      __builtin_amdgcn_s_setprio(1);
#pragma unroll
      for (int ks = 0; ks < 4; ks++)
#pragma unroll
        for (int kf = 0; kf < 4; kf++) {
          bf16x8 kfrag = *(const bf16x8*)&Kl[cur][kidx(kf * 16 + lr, ks * 64 + lg * 16)];
          sf[kf][0] = __builtin_amdgcn_mfma_f32_16x16x32_bf16(kfrag, qf[0][ks], sf[kf][0], 0, 0, 0);
          sf[kf][1] = __builtin_amdgcn_mfma_f32_16x16x32_bf16(kfrag, qf[1][ks], sf[kf][1], 0, 0, 0);
        }
      __builtin_amdgcn_s_setprio(0);

      float sv[2][4][4];
      float mx[2];
#pragma unroll
      for (int mf = 0; mf < 2; mf++) {
        int qg = q0w + mf * 16 + lr;
        mx[mf] = -3.0e38f;
#pragma unroll
        for (int kf = 0; kf < 4; kf++) {
          int kvb = kv0 + (kf >> 1) * 32 + (kf & 1) * 4 + lg * 8;
#pragma unroll
          for (int r = 0; r < 4; r++) {
            float x = sf[kf][mf][r];
            if (need_mask) x = (kvb + r <= qg) ? x : -3.0e38f;
            sv[mf][kf][r] = x;
            mx[mf] = fmaxf(mx[mf], x);
          }
        }
        mx[mf] = fmaxf(mx[mf], __shfl_xor(mx[mf], 16));
        mx[mf] = fmaxf(mx[mf], __shfl_xor(mx[mf], 32));
      }

      bool need = (mx[0] > m_r[0] + RTHR) | (mx[1] > m_r[1] + RTHR);
      if (__any(need)) {
        float scs[2];
#pragma unroll
        for (int mf = 0; mf < 2; mf++) {
          float mnew = fmaxf(m_r[mf], mx[mf]);
          scs[mf] = __builtin_amdgcn_exp2f((m_r[mf] - mnew) * SL2E);
          m_r[mf] = mnew;
          l_r[mf] *= scs[mf];
        }
#pragma unroll
        for (int mf = 0; mf < 2; mf++) {
#pragma unroll
          for (int r = 0; r < 4; r++) {
            float sa = __shfl(scs[mf], (lane & 0x30) | (lg * 4 + r));
#pragma unroll
            for (int f = 0; f < 8; f++) acc[mf][f][r] *= sa;
          }
        }
      }

      bf16x8 pf[2][2];
#pragma unroll
      for (int mf = 0; mf < 2; mf++) {
        float rs = 0.f;
#pragma unroll
        for (int kf = 0; kf < 4; kf++)
#pragma unroll
          for (int r = 0; r < 4; r++) {
            float p = __builtin_amdgcn_exp2f((sv[mf][kf][r] - m_r[mf]) * SL2E);
            sv[mf][kf][r] = p;
            rs += p;
          }
        rs += __shfl_xor(rs, 16);
        rs += __shfl_xor(rs, 32);
        l_r[mf] += rs;
#pragma unroll
        for (int ks2 = 0; ks2 < 2; ks2++) {
          bf16x8 t2;
#pragma unroll
          for (int r = 0; r < 4; r++) {
            t2[r] = (__bf16)sv[mf][2 * ks2][r];
            t2[4 + r] = (__bf16)sv[mf][2 * ks2 + 1][r];
          }
          pf[mf][ks2] = t2;
        }
      }

      __builtin_amdgcn_s_setprio(1);
#pragma unroll
      for (int ks2 = 0; ks2 < 2; ks2++)
#pragma unroll
        for (int f = 0; f < 8; f++) {
          bf16x8 vf = *(const bf16x8*)&Vl[cur][vidx(f * 16 + lr, ks2 * 64 + lg * 16)];
          acc[0][f] = __builtin_amdgcn_mfma_f32_16x16x32_bf16(pf[0][ks2], vf, acc[0][f], 0, 0, 0);
          acc[1][f] = __builtin_amdgcn_mfma_f32_16x16x32_bf16(pf[1][ks2], vf, acc[1][f], 0, 0, 0);
        }
      __builtin_amdgcn_s_setprio(0);
    }
    __syncthreads();
    cur ^= 1;
  }

#pragma unroll
  for (int mf = 0; mf < 2; mf++) {
    float invl = 1.0f / l_r[mf];
#pragma unroll
    for (int r = 0; r < 4; r++) {
      float ia = __shfl(invl, (lane & 0x30) | (lg * 4 + r));
      int rowg = b * S_LEN + q0w + mf * 16 + lg * 4 + r;
#pragma unroll
      for (int f = 0; f < 8; f++) {
        int colg = h * DKH + f * 16 + lr;
        ctx[(size_t)rowg * DM + colg] = f2bf(acc[mf][f][r] * ia);
      }
    }
  }
}

extern "C" void kernel_launch(void* const* d_in, const int* in_sizes, int n_in,
                              void* d_out, int out_size, void* d_ws, size_t ws_size,
                              hipStream_t stream) {
  const float* x = (const float*)d_in[0];
  const float* Wq = (const float*)d_in[1];
  const float* Wk = (const float*)d_in[2];
  const float* Wv = (const float*)d_in[3];
  const float* Wo = (const float*)d_in[4];
  float* out = (float*)d_out;

  char* ws = (char*)d_ws;
  size_t off = 0;
  auto alloc = [&](size_t bytes) -> char* {
    char* p = ws + off;
    off += (bytes + 255) & ~(size_t)255;
    return p;
  };
  u16* xb = (u16*)alloc((size_t)NROWS * DM * 2);     // reused as ctx
  u16* wqkv = (u16*)alloc((size_t)3 * DM * DM * 2);  // [Wq;Wk;Wv] rows
  u16* wob = (u16*)alloc((size_t)DM * DM * 2);
  u16* Qb = (u16*)alloc((size_t)NROWS * DM * 2);
  u16* Kb = (u16*)alloc((size_t)NROWS * DM * 2);
  u16* Vtb = (u16*)alloc((size_t)NROWS * DM * 2);
  float2* ctab = (float2*)alloc((size_t)S_LEN * 64 * 8);
  u16* ctx = xb;

  // allow >64KB dynamic LDS (host-side attribute; capture-safe)
  hipFuncSetAttribute((const void*)gemm256_kernel<3, 2>,
                      hipFuncAttributeMaxDynamicSharedMemorySize, 65536 + 2 * 192 * 128);
  hipFuncSetAttribute((const void*)gemm256_kernel<2, 0>,
                      hipFuncAttributeMaxDynamicSharedMemorySize, 65536 + 2 * 128 * 128);

  cast_all_kernel<<<2048, 256, 0, stream>>>(x, Wq, Wk, Wv, Wo, xb, wqkv, wob);
  rope_table_kernel<<<(S_LEN * 64 + 255) / 256, 256, 0, stream>>>(ctab);

  // fused QKV projection + RoPE + V-transpose: A=xb [4096x2048], B=wqkv [6144x2048]
  // BN=192 -> grid 32x16 = 512 blocks = 2 exact dispatch rounds at 1 block/CU
  gemm256_kernel<3, 2><<<dim3(3 * DM / 192, NROWS / 256), 512, 65536 + 2 * 192 * 128, stream>>>(
      xb, wqkv, Qb, Kb, Vtb, ctab, NROWS, 3 * DM, DM);

  attn_kernel<<<dim3(NB * NH, S_LEN / 128), 256, 0, stream>>>(Qb, Kb, Vtb, ctx);

  // output projection: A=ctx [4096x2048], B=wob [2048x2048] -> f32 out
  // BN=128 -> grid 16x16 = 256 blocks = 1 exact dispatch round
  gemm256_kernel<2, 0><<<dim3(DM / 128, NROWS / 256), 512, 65536 + 2 * 128 * 128, stream>>>(
      ctx, wob, out, nullptr, nullptr, nullptr, NROWS, DM, DM);
}